// Round 6
// baseline (759.302 us; speedup 1.0000x reference)
//
#include <hip/hip_runtime.h>
#include <hip/hip_bf16.h>
#include <math.h>

constexpr int N = 65536;
constexpr int C = 192;
constexpr int O = 192;
constexpr int H = 384;
constexpr int E = 8;
constexpr int B = 4;
constexpr int R = 8;
constexpr int F = 64;
constexpr int GIN = C + F + 2;   // 258
constexpr int K = 10240;
constexpr int TM = 32;           // tokens per expert-tile
constexpr int NBKT = 16384;      // 14-bit bucket histogram
constexpr int PCH = 16;          // chunks per expert for select passes
constexpr int CAP = 32768;       // candidate capacity per expert (>>10x margin)
constexpr int GT = 32;           // tokens per gate block
constexpr int TCAP = 2048;       // selD tie fast-path capacity

typedef unsigned short ushort;
typedef __attribute__((ext_vector_type(8))) short bf16x8;
typedef __attribute__((ext_vector_type(4))) float f32x4;
typedef __attribute__((ext_vector_type(4))) double f64x4;
typedef __attribute__((ext_vector_type(4))) ushort ushort4v;

#define MFMA(a, b, c) __builtin_amdgcn_mfma_f32_16x16x32_bf16(a, b, c, 0, 0, 0)
#define DMFMA(a, b, c) __builtin_amdgcn_mfma_f64_16x16x4f64(a, b, c, 0, 0, 0)

__device__ inline ushort f2bf(float f) {
  union { float f; unsigned u; } v; v.f = f;
  unsigned r = v.u + 0x7FFFu + ((v.u >> 16) & 1u);
  return (ushort)(r >> 16);
}

__device__ inline unsigned long long dkey(double d) {
  unsigned long long u = (unsigned long long)__double_as_longlong(d);
  return (u & 0x8000000000000000ULL) ? ~u : (u | 0x8000000000000000ULL);
}

__device__ inline double wave_reduce_sum(double v) {
  #pragma unroll
  for (int off = 32; off; off >>= 1) v += __shfl_down(v, off);
  return v;  // valid on lane 0
}

// ---------- coalesced f32->bf16 tile transpose (per-expert matrices) ----------
// src[e][rows][cols] (f32) -> dst[e][cols][rows] (bf16). 32x32 tiles, pad+1.
__global__ __launch_bounds__(256) void transpose_bf16_kernel(
    const float* __restrict__ src, ushort* __restrict__ dst,
    int rows, int cols) {
  __shared__ float tile[32][33];
  int e = blockIdx.y;
  int tilesPerRow = cols >> 5;
  int tr = blockIdx.x / tilesPerRow;
  int tc = blockIdx.x % tilesPerRow;
  int r0 = tr * 32, c0 = tc * 32;
  const float* s = src + (size_t)e * rows * cols;
  ushort* d = dst + (size_t)e * rows * cols;
  int tx = threadIdx.x & 31, ty = threadIdx.x >> 5;   // 32 x 8
  #pragma unroll
  for (int k = 0; k < 4; ++k)
    tile[ty + 8 * k][tx] = s[(size_t)(r0 + ty + 8 * k) * cols + c0 + tx];
  __syncthreads();
  #pragma unroll
  for (int k = 0; k < 4; ++k)
    d[(size_t)(c0 + ty + 8 * k) * rows + r0 + tx] = f2bf(tile[tx][ty + 8 * k]);
}

// ---------- convert LoRA weights to bf16; precompute C0/CB ----------
__global__ __launch_bounds__(256) void convert_kernel(
    const float* __restrict__ A1, const float* __restrict__ B1,
    const float* __restrict__ A2, const float* __restrict__ B2,
    const float* __restrict__ ln_g, const float* __restrict__ ln_b,
    const float* __restrict__ Wg,
    ushort* __restrict__ A1t, ushort* __restrict__ B1t,
    ushort* __restrict__ A2t, ushort* __restrict__ B2t,
    double* __restrict__ C0g, double* __restrict__ CBg) {
  const int s3 = E * 32 * C;     // A1t[e][br][c]
  const int s4 = E * H * 32;     // B1t[e][h][br]
  const int s5 = E * 32 * H;     // A2t[e][br][h]
  const int s6 = E * O * 32;     // B2t[e][o][br]
  // C0[e] = sum_i g[i]*Wg[i][e]; CB[e] = sum_i b[i]*Wg[i][e]  (f64, once)
  if (blockIdx.x == 0 && threadIdx.x < 16) {
    int e = threadIdx.x & 7;
    double acc = 0.0;
    if (threadIdx.x < 8) {
      for (int i = 0; i < GIN; ++i) acc += (double)ln_g[i] * (double)Wg[i * E + e];
      C0g[e] = acc;
    } else {
      for (int i = 0; i < GIN; ++i) acc += (double)ln_b[i] * (double)Wg[i * E + e];
      CBg[e] = acc;
    }
  }
  int tid = blockIdx.x * 256 + threadIdx.x;
  if (tid < s3) {
    int e = tid / (32 * C), rem = tid % (32 * C), br = rem / C, c = rem % C;
    int b = br >> 3, r = br & 7;
    A1t[tid] = f2bf(A1[(((size_t)e * B + b) * C + c) * R + r]);
  } else if ((tid -= s3) < s4) {
    int e = tid / (H * 32), rem = tid % (H * 32), h = rem / 32, br = rem % 32;
    B1t[tid] = f2bf(B1[((size_t)e * 32 + br) * H + h]);
  } else if ((tid -= s4) < s5) {
    int e = tid / (32 * H), rem = tid % (32 * H), br = rem / H, h = rem % H;
    int b = br >> 3, r = br & 7;
    A2t[tid] = f2bf(A2[(((size_t)e * B + b) * H + h) * R + r]);
  } else if ((tid -= s5) < s6) {
    int e = tid / (O * 32), rem = tid % (O * 32), o = rem / 32, br = rem % 32;
    B2t[tid] = f2bf(B2[((size_t)e * 32 + br) * O + o]);
  }
}

// ---------- gate: all reductions via f64 MFMA; near-zero shuffle traffic ----
__global__ __launch_bounds__(512, 4) void gate_kernel(
    const float* __restrict__ x, const float* __restrict__ xp,
    const float* __restrict__ Wz, const float* __restrict__ ln_g,
    const float* __restrict__ ln_b, const float* __restrict__ Wg,
    const float* __restrict__ bg, const double* __restrict__ C0g,
    const double* __restrict__ CBg, double* __restrict__ logitsT) {
  __shared__ float xs[GT][196];       // 25.1 KiB, row-major (MFMA A reads)
  __shared__ double Zs[GT][65];       // 16.6 KiB
  __shared__ double Wgp[256][10];     // 20 KiB: g*Wg cols 0..7, col8=1, col9=0
  __shared__ double Sp[2][16][10];    // 2.5 KiB x-GEMM k-half partials
  __shared__ double Sfin[GT][12];     // 3 KiB  S'x[t][e]
  __shared__ double Sfz[GT][12];      // 3 KiB  S'z[t][e], col8 = sum(Z)
  __shared__ double s2zs[GT];         // sum(Z^2)
  __shared__ double mus[GT], sds[GT], sxs[GT], s2xs[GT];

  int tid = threadIdx.x;
  int n0 = blockIdx.x * GT;
  int w = tid >> 6, lane = tid & 63;
  int arow = lane & 15, kg = lane >> 4;
  int tt = w >> 2, ft = w & 3;

  // ---- stage G = g.*Wg (f64) ----
  for (int u = tid; u < 256 * 8; u += 512) {
    int k = u >> 3, e = u & 7;
    Wgp[k][e] = (double)ln_g[k] * (double)Wg[k * E + e];
  }
  if (tid < 256) { Wgp[tid][8] = 1.0; Wgp[tid][9] = 0.0; }

  // ---- stage x (f32, row-major) + fused residual/LN stats ----
  {
    int t = tid >> 4, ch = tid & 15;
    const float* xr = x + (size_t)(n0 + t) * C + ch * 12;
    const float* pr = xp + (size_t)(n0 + t) * C + ch * 12;
    double pa = 0.0, pa2 = 0.0, px = 0.0, px2 = 0.0;
    #pragma unroll
    for (int j = 0; j < 3; ++j) {
      float4 xv = *(const float4*)(xr + j * 4);
      float4 pv = *(const float4*)(pr + j * 4);
      *(float4*)&xs[t][ch * 12 + j * 4] = xv;
      float xa[4] = {xv.x, xv.y, xv.z, xv.w};
      float pp[4] = {pv.x, pv.y, pv.z, pv.w};
      #pragma unroll
      for (int q2 = 0; q2 < 4; ++q2) {
        double dx = (double)xa[q2];
        px += dx; px2 += dx * dx;
        double ad = (double)fabsf(xa[q2] - pp[q2]);
        pa += ad; pa2 += ad * ad;
      }
    }
    #pragma unroll
    for (int off = 8; off; off >>= 1) {
      pa += __shfl_down(pa, off);
      pa2 += __shfl_down(pa2, off);
      px += __shfl_down(px, off);
      px2 += __shfl_down(px2, off);
    }
    if (ch == 0) {
      double mean_a = pa * (1.0 / 192.0);
      double var_a = (pa2 - pa * pa * (1.0 / 192.0)) * (1.0 / 191.0);
      var_a = var_a > 0.0 ? var_a : 0.0;
      mus[t] = log1p(mean_a);
      sds[t] = log1p(sqrt(var_a));
      sxs[t] = px; s2xs[t] = px2;
    }
  }

  // ---- decode f64 MFMA D slot->(row,col) with two probes ----
  int rowIdx[4], colIdx[4];
  {
    f64x4 z4 = {0.0, 0.0, 0.0, 0.0};
    double pr = (double)arow;
    double pk = (kg == 0) ? 1.0 : 0.0;
    f64x4 p1 = DMFMA(pr, pk, z4);
    f64x4 p2 = DMFMA(pk, pr, z4);
    #pragma unroll
    for (int d = 0; d < 4; ++d) {
      rowIdx[d] = ((int)p1[d]) & 15;
      colIdx[d] = ((int)p2[d]) & 15;
    }
  }

  __syncthreads();

  // ---- Z = x @ Wz via f64 MFMA ----
  {
    f64x4 acc[2];
    acc[0] = (f64x4){0.0, 0.0, 0.0, 0.0}; acc[1] = acc[0];
    float bxa[24];
    #pragma unroll
    for (int s = 0; s < 24; ++s)
      bxa[s] = Wz[(4 * s + kg) * F + ft * 16 + arow];
    #pragma unroll
    for (int s = 0; s < 24; ++s) {
      double a = (double)xs[tt * 16 + arow][4 * s + kg];
      acc[s & 1] = DMFMA(a, (double)bxa[s], acc[s & 1]);
    }
    #pragma unroll
    for (int s = 0; s < 24; ++s)
      bxa[s] = Wz[(96 + 4 * s + kg) * F + ft * 16 + arow];
    #pragma unroll
    for (int s = 0; s < 24; ++s) {
      double a = (double)xs[tt * 16 + arow][96 + 4 * s + kg];
      acc[s & 1] = DMFMA(a, (double)bxa[s], acc[s & 1]);
    }
    f64x4 r = acc[0] + acc[1];
    #pragma unroll
    for (int d = 0; d < 4; ++d)
      Zs[tt * 16 + rowIdx[d]][ft * 16 + colIdx[d]] = r[d];
  }
  __syncthreads();

  // ---- reduction GEMMs (f64 MFMA) ----
  int ccol = arow < 9 ? arow : 9;   // col9 holds 0.0
  f64x4 rx = {0.0, 0.0, 0.0, 0.0};  // kh==1 partial held across barrier
  int xt2 = 0;
  if (w < 4) {
    int t2 = w >> 1, kh = w & 1; xt2 = t2;
    int kbase = kh * 96;
    f64x4 acc[2];
    acc[0] = (f64x4){0.0, 0.0, 0.0, 0.0}; acc[1] = acc[0];
    #pragma unroll
    for (int s = 0; s < 24; ++s) {
      int k = kbase + 4 * s + kg;
      double a = (double)xs[t2 * 16 + arow][k];
      acc[s & 1] = DMFMA(a, Wgp[k][ccol], acc[s & 1]);
    }
    f64x4 r = acc[0] + acc[1];
    if (kh == 0) {
      #pragma unroll
      for (int d = 0; d < 4; ++d)
        if (colIdx[d] < 9) Sp[t2][rowIdx[d]][colIdx[d]] = r[d];
    } else {
      rx = r;
    }
  } else {
    int zq = w - 4; int t2 = zq & 1; int sq = zq >> 1;
    f64x4 acc[2];
    acc[0] = (f64x4){0.0, 0.0, 0.0, 0.0}; acc[1] = acc[0];
    #pragma unroll
    for (int s = 0; s < 16; ++s) {
      double a = Zs[t2 * 16 + arow][4 * s + kg];
      if (sq) a = a * a;
      acc[s & 1] = DMFMA(a, Wgp[192 + 4 * s + kg][ccol], acc[s & 1]);
    }
    f64x4 r = acc[0] + acc[1];
    if (!sq) {
      #pragma unroll
      for (int d = 0; d < 4; ++d)
        if (colIdx[d] < 9) Sfz[t2 * 16 + rowIdx[d]][colIdx[d]] = r[d];
    } else {
      #pragma unroll
      for (int d = 0; d < 4; ++d)
        if (colIdx[d] == 8) s2zs[t2 * 16 + rowIdx[d]] = r[d];
    }
  }
  __syncthreads();
  if (w < 4 && (w & 1)) {
    #pragma unroll
    for (int d = 0; d < 4; ++d)
      if (colIdx[d] < 9)
        Sfin[xt2 * 16 + rowIdx[d]][colIdx[d]] =
            rx[d] + Sp[xt2][rowIdx[d]][colIdx[d]];
  }
  __syncthreads();

  // ---- assembly: thread = t*8 + e ----
  if (tid < GT * E) {
    int t = tid >> 3, e = tid & 7;
    int n = n0 + t;
    double mu = mus[t], sd = sds[t];
    double s = sxs[t] + Sfz[t][8] + mu + sd;
    double q = s2xs[t] + s2zs[t] + mu * mu + sd * sd;
    double m_ = s * (1.0 / 258.0);
    double v_ = q * (1.0 / 258.0) - m_ * m_;
    v_ = v_ > 0.0 ? v_ : 0.0;
    double rstd = 1.0 / sqrt(v_ + 1e-5);
    double G256e = (double)ln_g[256] * (double)Wg[256 * E + e];
    double G257e = (double)ln_g[257] * (double)Wg[257 * E + e];
    double S = Sfin[t][e] + Sfz[t][e] + mu * G256e + sd * G257e;
    double logit = rstd * S - rstd * m_ * C0g[e] + CBg[e] + (double)bg[e];
    logitsT[(size_t)e * N + n] = logit;
  }
}

// ---------- select stage A: per-chunk 14-bit bucket histogram ----------
__global__ __launch_bounds__(256) void selA_kernel(
    const double* __restrict__ logitsT, unsigned* __restrict__ gh) {
  __shared__ unsigned hist[NBKT];   // 64 KiB
  int e = blockIdx.y;
  const double* L = logitsT + (size_t)e * N + blockIdx.x * (N / PCH);
  for (int i = threadIdx.x; i < NBKT; i += 256) hist[i] = 0;
  __syncthreads();
  for (int i = threadIdx.x; i < N / PCH; i += 256) {
    unsigned long long k = dkey(L[i]);
    atomicAdd(&hist[(unsigned)(k >> 50)], 1u);
  }
  __syncthreads();
  unsigned* ghe = gh + (size_t)e * NBKT;
  for (int i = threadIdx.x; i < NBKT; i += 256) {
    unsigned v = hist[i];
    if (v) atomicAdd(&ghe[i], v);
  }
}

// ---------- select stage B: find boundary bucket + count above ----------
__global__ __launch_bounds__(256) void selB_kernel(
    const unsigned* __restrict__ gh, int* __restrict__ boundB,
    int* __restrict__ countAbove) {
  int e = blockIdx.x;
  const unsigned* ghe = gh + (size_t)e * NBKT;
  __shared__ unsigned chunkSum[256];
  unsigned s = 0;
  int base = threadIdx.x * 64;
  for (int i = 0; i < 64; ++i) s += ghe[base + i];
  chunkSum[threadIdx.x] = s;
  __syncthreads();
  if (threadIdx.x == 0) {
    long long acc = 0;
    for (int t = 255; t >= 0; --t) {
      if (acc + (long long)chunkSum[t] >= K) {
        for (int b = t * 64 + 63; b >= t * 64; --b) {
          unsigned hv = ghe[b];
          if (acc + (long long)hv >= K) {
            boundB[e] = b; countAbove[e] = (int)acc; return;
          }
          acc += hv;
        }
      }
      acc += chunkSum[t];
    }
    boundB[e] = 0; countAbove[e] = 0;  // unreachable safety
  }
}

// ---------- select stage C: compact boundary-bucket candidates ----------
__global__ __launch_bounds__(256) void selC_kernel(
    const double* __restrict__ logitsT, const int* __restrict__ boundB,
    int* __restrict__ candCnt, unsigned long long* __restrict__ candKey,
    int* __restrict__ candIdx) {
  int e = blockIdx.y;
  unsigned bb = (unsigned)boundB[e];
  int base = blockIdx.x * (N / PCH);
  const double* L = logitsT + (size_t)e * N;
  int lane = threadIdx.x & 63;
  unsigned long long below = (1ULL << lane) - 1ULL;
  for (int i0 = 0; i0 < N / PCH; i0 += 256) {
    int n = base + i0 + threadIdx.x;
    unsigned long long k = dkey(L[n]);
    bool match = ((unsigned)(k >> 50) == bb);
    unsigned long long mk = __ballot(match);
    if (match) {
      int leader = __ffsll((long long)mk) - 1;
      int cbase = 0;
      if (lane == leader) cbase = atomicAdd(&candCnt[e], __popcll(mk));
      cbase = __shfl(cbase, leader);
      int pos = cbase + __popcll(mk & below);
      if (pos < CAP) {
        candKey[(size_t)e * CAP + pos] = k;
        candIdx[(size_t)e * CAP + pos] = n;
      }
    }
  }
}

// ---------- select stage D: exact radix on candidates + tie cut ----------
// Tie cut: fast path compacts tie indices (f64 keys are ~always distinct, so
// cT is tiny) and rank-selects in LDS; falls back to the global binary search
// only if cT > TCAP.
__global__ __launch_bounds__(256) void selD_kernel(
    const unsigned long long* __restrict__ candKey, const int* __restrict__ candIdx,
    const int* __restrict__ candCnt, const int* __restrict__ countAbove,
    unsigned long long* __restrict__ Tkey, int* __restrict__ tieCut) {
  int e = blockIdx.x;
  int c = candCnt[e]; if (c > CAP) c = CAP;
  int need = K - countAbove[e];
  const unsigned long long* keys = candKey + (size_t)e * CAP;
  const int* idxs = candIdx + (size_t)e * CAP;
  __shared__ unsigned hist[256];
  __shared__ unsigned long long spref;
  __shared__ int srem;
  __shared__ int red[256];
  __shared__ int tieIdx[TCAP];
  __shared__ int tieCnt;
  int tid = threadIdx.x;
  if (tid == 0) { spref = 0ULL; srem = need; }
  __syncthreads();
  for (int pass = 7; pass >= 0; --pass) {
    hist[tid] = 0;
    __syncthreads();
    unsigned long long pref = spref;
    unsigned long long mhi = (pass == 7) ? 0ULL : (~0ULL << ((pass + 1) * 8));
    for (int i = tid; i < c; i += 256) {
      unsigned long long k = keys[i];
      if ((k & mhi) == pref)
        atomicAdd(&hist[(unsigned)((k >> (pass * 8)) & 0xFF)], 1u);
    }
    __syncthreads();
    if (tid == 0) {
      int rem = srem;
      int b = 255;
      for (; b > 0; --b) {
        int cc = (int)hist[b];
        if (cc >= rem) break;
        rem -= cc;
      }
      srem = rem;
      spref = pref | ((unsigned long long)(unsigned)b << (pass * 8));
    }
    __syncthreads();
  }
  unsigned long long T = spref;
  int needT = srem;  // take needT lowest-index tokens among ==T

  // ---- compact tie indices ----
  if (tid == 0) tieCnt = 0;
  __syncthreads();
  for (int i = tid; i < c; i += 256) {
    if (keys[i] == T) {
      int p = atomicAdd(&tieCnt, 1);
      if (p < TCAP) tieIdx[p] = idxs[i];
    }
  }
  __syncthreads();
  int cT = tieCnt;
  if (cT <= TCAP) {
    // rank-count selection in LDS: find the needT-th smallest index (exact;
    // indices are distinct so rank == needT-1 identifies a unique entry)
    for (int j = tid; j < cT; j += 256) {
      int v = tieIdx[j];
      int rank = 0;
      for (int k2 = 0; k2 < cT; ++k2) rank += (tieIdx[k2] < v) ? 1 : 0;
      if (rank == needT - 1) tieCut[e] = v;
    }
    if (tid == 0) Tkey[e] = T;
    return;
  }
  // ---- fallback: global binary search (adversarial mass-tie case) ----
  int lo = 0, hi = N - 1;
  while (lo < hi) {
    int mid = (lo + hi) >> 1;
    int cnt = 0;
    for (int i = tid; i < c; i += 256)
      cnt += (keys[i] == T && idxs[i] <= mid) ? 1 : 0;
    red[tid] = cnt;
    __syncthreads();
    for (int off = 128; off; off >>= 1) {
      if (tid < off) red[tid] += red[tid + off];
      __syncthreads();
    }
    int total = red[0];
    __syncthreads();
    if (total >= needT) hi = mid; else lo = mid + 1;
  }
  if (tid == 0) { Tkey[e] = T; tieCut[e] = lo; }
}

// ---------- routing: mask, fallback, top-2 softmax, aggregated dispatch ----------
__global__ __launch_bounds__(256) void route_kernel(
    const double* __restrict__ logitsT, const unsigned long long* __restrict__ Tkey,
    const int* __restrict__ tieCut, int* __restrict__ cnt,
    int* __restrict__ list_tok, float* __restrict__ list_w,
    double* __restrict__ importance) {
  int n = blockIdx.x * 256 + threadIdx.x;
  int lane = threadIdx.x & 63;
  double l[E];
  unsigned selbits = 0;
  #pragma unroll
  for (int e = 0; e < E; ++e) {
    l[e] = logitsT[(size_t)e * N + n];
    unsigned long long k = dkey(l[e]);
    unsigned long long T = Tkey[e];
    bool sel = (k > T) || (k == T && n <= tieCut[e]);
    if (sel) selbits |= (1u << e);
  }
  if (selbits == 0) {
    int best = 0; double bv = l[0];
    #pragma unroll
    for (int e = 1; e < E; ++e) if (l[e] > bv) { bv = l[e]; best = e; }
    selbits = (1u << best);
  }
  int i0 = -1, i1 = -1;
  double v0 = -1e300, v1 = -1e300;
  #pragma unroll
  for (int e = 0; e < E; ++e) {
    if (selbits & (1u << e)) {
      double v = l[e];
      if (v > v0) { v1 = v0; i1 = i0; v0 = v; i0 = e; }
      else if (v > v1) { v1 = v; i1 = e; }
    }
  }
  double w0 = 1.0, w1 = 0.0;
  if (i1 >= 0) {
    double e1 = exp(v1 - v0);
    w0 = 1.0 / (1.0 + e1);
    w1 = e1 / (1.0 + e1);
  }
  float w0f = (float)w0;
  float w1f = (float)w1;
  bool app1 = (i1 >= 0) && (w1f > 0.0f);

  unsigned long long below = (1ULL << lane) - 1ULL;
  #pragma unroll
  for (int e = 0; e < E; ++e) {
    unsigned long long m0 = __ballot(i0 == e);
    unsigned long long m1 = __ballot(app1 && i1 == e);
    int c = __popcll(m0) + __popcll(m1);
    int basep = 0;
    if (lane == 0 && c) basep = atomicAdd(&cnt[e], c);
    basep = __shfl(basep, 0);
    if (i0 == e) {
      int idx = basep + __popcll(m0 & below);
      list_tok[e * N + idx] = n;
      list_w[e * N + idx] = w0f;
    }
    if (app1 && i1 == e) {
      int idx = basep + __popcll(m0) + __popcll(m1 & below);
      list_tok[e * N + idx] = n;
      list_w[e * N + idx] = w1f;
    }
    double v = 0.0;
    if (i0 == e) v += (double)w0f;
    if (app1 && i1 == e) v += (double)w1f;
    v = wave_reduce_sum(v);
    if (lane == 0 && v != 0.0) unsafeAtomicAdd(&importance[e], v);
  }
}

// ---------- fused expert MLP via bf16 MFMA ----------
// TM=32 (same memory pattern as the 166us r3 kernel) but 512 threads = 8
// waves on the same 44KB LDS -> 3 blocks/CU * 8 waves = 24 waves/CU (75%
// occupancy cap vs 37%). Long phases (h: 24 h-tiles, y: 24 (ot,half) units)
// split 3-per-wave; short t1/t2 phases keep the 4-wave mapping.
__global__ __launch_bounds__(512, 6) void expert_kernel(
    const float* __restrict__ x, const float* __restrict__ bw,
    const float* __restrict__ b1g, const float* __restrict__ b2g,
    const ushort* __restrict__ W1t, const ushort* __restrict__ W2t,
    const ushort* __restrict__ A1t, const ushort* __restrict__ B1t,
    const ushort* __restrict__ A2t, const ushort* __restrict__ B2t,
    const int* __restrict__ cnt, const int* __restrict__ list_tok,
    const float* __restrict__ list_w, float* __restrict__ out) {
  int e = blockIdx.y;
  int ce = cnt[e];
  int start = blockIdx.x * TM;
  if (start >= ce) return;
  int m = ce - start; if (m > TM) m = TM;

  __shared__ ushort xs[TM][200];   // pitch 400B: 16B-aligned rows
  __shared__ ushort hs[TM][392];
  __shared__ ushort t1w[TM][40];
  __shared__ ushort t2w[TM][40];
  __shared__ int stok[TM];
  __shared__ float swt[TM];
  __shared__ float bws[TM][B];

  int tid = threadIdx.x;
  if (tid < TM) {
    int idx = start + (tid < m ? tid : 0);
    stok[tid] = list_tok[e * N + idx];
    swt[tid] = (tid < m) ? list_w[e * N + idx] : 0.0f;
  }
  __syncthreads();
  // x -> bf16 LDS: 48 float4 chunks per token (C=192)
  for (int u = tid; u < TM * 48; u += 512) {
    int t = u / 48, ch = u % 48;
    float4 v = *(const float4*)(x + (size_t)stok[t] * C + ch * 4);
    ushort4v o4;
    o4.x = f2bf(v.x); o4.y = f2bf(v.y); o4.z = f2bf(v.z); o4.w = f2bf(v.w);
    *(ushort4v*)&xs[t][ch * 4] = o4;
  }
  if (tid < TM * B) {
    int t = tid >> 2, b = tid & 3;
    bws[t][b] = bw[(size_t)stok[t] * B + b];
  }
  __syncthreads();

  int w = tid >> 6, lane = tid & 63, q = lane >> 4, mr = lane & 15;

  // ---- t1 = x @ A1e, scaled by 2*bw -> t1w (bf16, A-layout-ready)
  if (w < 4) {
    int mt = w >> 1, nt = w & 1;
    const ushort* A1te = A1t + ((size_t)e * 32 + nt * 16 + mr) * C;
    f32x4 acc = {0.f, 0.f, 0.f, 0.f};
    #pragma unroll
    for (int ks = 0; ks < 6; ++ks) {
      bf16x8 a = *(const bf16x8*)&xs[mt * 16 + mr][ks * 32 + q * 8];
      bf16x8 b = *(const bf16x8*)(A1te + ks * 32 + q * 8);
      acc = MFMA(a, b, acc);
    }
    int brc = nt * 16 + mr, bb = brc >> 3;
    #pragma unroll
    for (int r = 0; r < 4; ++r) {
      int t = mt * 16 + q * 4 + r;
      t1w[t][brc] = f2bf(2.0f * acc[r] * bws[t][bb]);
    }
  }
  __syncthreads();

  // ---- h = gelu(x@W1 + b1 + t1w@B1): 24 h-tiles, 3 per wave
  {
    const ushort* W1te = W1t + (size_t)e * H * C;
    const ushort* B1te = B1t + (size_t)e * H * 32;
    for (int ht = w * 3; ht < w * 3 + 3; ++ht) {
      int h = ht * 16 + mr;
      float bi = b1g[e * H + h];
      f32x4 acc0 = {bi, bi, bi, bi}, acc1 = acc0;
      bf16x8 bb = *(const bf16x8*)(B1te + h * 32 + q * 8);
      acc0 = MFMA(*(const bf16x8*)&t1w[mr][q * 8], bb, acc0);
      acc1 = MFMA(*(const bf16x8*)&t1w[16 + mr][q * 8], bb, acc1);
      #pragma unroll
      for (int ks = 0; ks < 6; ++ks) {
        bf16x8 wb = *(const bf16x8*)(W1te + (size_t)h * C + ks * 32 + q * 8);
        acc0 = MFMA(*(const bf16x8*)&xs[mr][ks * 32 + q * 8], wb, acc0);
        acc1 = MFMA(*(const bf16x8*)&xs[16 + mr][ks * 32 + q * 8], wb, acc1);
      }
      #pragma unroll
      for (int r = 0; r < 4; ++r) {
        float v0 = acc0[r], v1 = acc1[r];
        v0 = 0.5f * v0 * (1.0f + erff(v0 * 0.70710678118654752f));
        v1 = 0.5f * v1 * (1.0f + erff(v1 * 0.70710678118654752f));
        hs[q * 4 + r][h] = f2bf(v0);
        hs[16 + q * 4 + r][h] = f2bf(v1);
      }
    }
  }
  __syncthreads();

  // ---- t2 = h @ A2e, scaled by 2*bw -> t2w
  if (w < 4) {
    int mt = w >> 1, nt = w & 1;
    const ushort* A2te = A2t + ((size_t)e * 32 + nt * 16 + mr) * H;
    f32x4 acc = {0.f, 0.f, 0.f, 0.f};
    #pragma unroll
    for (int ks = 0; ks < 12; ++ks) {
      bf16x8 a = *(const bf16x8*)&hs[mt * 16 + mr][ks * 32 + q * 8];
      bf16x8 b = *(const bf16x8*)(A2te + ks * 32 + q * 8);
      acc = MFMA(a, b, acc);
    }
    int brc = nt * 16 + mr, bb = brc >> 3;
    #pragma unroll
    for (int r = 0; r < 4; ++r) {
      int t = mt * 16 + q * 4 + r;
      t2w[t][brc] = f2bf(2.0f * acc[r] * bws[t][bb]);
    }
  }
  __syncthreads();

  // ---- y = h@W2 + b2 + t2w@B2: 24 (o-tile, token-half) units, 3 per wave
  {
    const ushort* W2te = W2t + (size_t)e * O * H;
    const ushort* B2te = B2t + (size_t)e * O * 32;
    #pragma unroll
    for (int i = 0; i < 3; ++i) {
      int uo = w * 3 + i;
      int ot = uo >> 1, sh = uo & 1;
      int o = ot * 16 + mr;
      int r0 = sh * 16;
      float bi = b2g[e * O + o];
      f32x4 acc0 = {bi, bi, bi, bi};
      bf16x8 bb = *(const bf16x8*)(B2te + o * 32 + q * 8);
      acc0 = MFMA(*(const bf16x8*)&t2w[r0 + mr][q * 8], bb, acc0);
      #pragma unroll
      for (int ks = 0; ks < 12; ++ks) {
        bf16x8 wb = *(const bf16x8*)(W2te + (size_t)o * H + ks * 32 + q * 8);
        acc0 = MFMA(*(const bf16x8*)&hs[r0 + mr][ks * 32 + q * 8], wb, acc0);
      }
      #pragma unroll
      for (int r = 0; r < 4; ++r) {
        int t0 = r0 + q * 4 + r;
        if (t0 < m)
          unsafeAtomicAdd(&out[(size_t)stok[t0] * O + o], swt[t0] * acc0[r]);
      }
    }
  }
}

// ---------- load-balance aux loss ----------
__global__ void loss_kernel(const double* __restrict__ importance,
                            const int* __restrict__ cnt,
                            float* __restrict__ loss_out) {
  if (threadIdx.x == 0 && blockIdx.x == 0) {
    double im = 0.0, lm = 0.0;
    for (int e = 0; e < E; ++e) { im += importance[e]; lm += (double)cnt[e]; }
    im *= (1.0 / E); lm *= (1.0 / E);
    double iv = 0.0, lv = 0.0;
    for (int e = 0; e < E; ++e) {
      double di = importance[e] - im; iv += di * di;
      double dl = (double)cnt[e] - lm; lv += dl * dl;
    }
    iv *= (1.0 / E); lv *= (1.0 / E);
    double loss = (iv / (im * im + 1e-10) + lv / (lm * lm + 1e-10)) * 0.01;
    loss_out[0] = (float)loss;
  }
}

extern "C" void kernel_launch(void* const* d_in, const int* in_sizes, int n_in,
                              void* d_out, int out_size, void* d_ws, size_t ws_size,
                              hipStream_t stream) {
  const float* x    = (const float*)d_in[0];
  const float* bw   = (const float*)d_in[1];
  const float* xp   = (const float*)d_in[2];
  const float* Wz   = (const float*)d_in[3];
  const float* ln_g = (const float*)d_in[4];
  const float* ln_b = (const float*)d_in[5];
  const float* Wg   = (const float*)d_in[6];
  const float* bg   = (const float*)d_in[7];
  const float* W1   = (const float*)d_in[8];
  const float* b1   = (const float*)d_in[9];
  const float* W2   = (const float*)d_in[10];
  const float* b2   = (const float*)d_in[11];
  const float* A1   = (const float*)d_in[12];
  const float* B1   = (const float*)d_in[13];
  const float* A2   = (const float*)d_in[14];
  const float* B2   = (const float*)d_in[15];
  float* out = (float*)d_out;

  const size_t MB = 1024 * 1024;
  char* ws = (char*)d_ws;
  double* logitsT = (double*)ws;                           // 4 MiB
  int*    list_tok = (int*)(ws + 4 * MB);                  // 2 MiB
  float*  list_w   = (float*)(ws + 6 * MB);                // 2 MiB
  char*   hdr      = ws + 8 * MB;                          // 4 KiB
  unsigned long long* Tkey = (unsigned long long*)hdr;     // @0
  int*    tieCut = (int*)(hdr + 64);                       // @64
  int*    cnt    = (int*)(hdr + 96);                       // @96
  double* importance = (double*)(hdr + 128);               // @128..192
  int*    boundB = (int*)(hdr + 256);
  int*    countAbove = (int*)(hdr + 288);
  int*    candCnt = (int*)(hdr + 320);
  double* C0g = (double*)(hdr + 512);                      // @512..576
  double* CBg = (double*)(hdr + 576);                      // @576..640
  ushort* W1t = (ushort*)(ws + 8 * MB + 4096);             // ~3 MiB of bf16 weights
  ushort* W2t = W1t + (size_t)E * H * C;
  ushort* A1t = W2t + (size_t)E * O * H;
  ushort* B1t = A1t + (size_t)E * 32 * C;
  ushort* A2t = B1t + (size_t)E * H * 32;
  ushort* B2t = A2t + (size_t)E * 32 * H;
  unsigned* gh = (unsigned*)(ws + 12 * MB);                // 512 KiB
  unsigned long long* candKey = (unsigned long long*)(ws + 13 * MB);  // 2 MiB
  int* candIdx = (int*)(ws + 15 * MB);                     // 1 MiB

  hipMemsetAsync(d_out, 0, (size_t)(N * O + 1) * sizeof(float), stream);
  hipMemsetAsync(hdr + 96, 0, 352 - 96, stream);  // cnt, importance, sel headers
  hipMemsetAsync(gh, 0, (size_t)E * NBKT * sizeof(unsigned), stream);

  // big weights: coalesced LDS tile transpose; LoRA smalls: element kernel
  transpose_bf16_kernel<<<dim3((C / 32) * (H / 32), E), 256, 0, stream>>>(
      W1, W1t, C, H);
  transpose_bf16_kernel<<<dim3((H / 32) * (O / 32), E), 256, 0, stream>>>(
      W2, W2t, H, O);
  int convN = (E * 32 * C) * 2 + (E * H * 32) * 2;
  convert_kernel<<<(convN + 255) / 256, 256, 0, stream>>>(
      A1, B1, A2, B2, ln_g, ln_b, Wg, A1t, B1t, A2t, B2t, C0g, CBg);
  gate_kernel<<<N / GT, 512, 0, stream>>>(x, xp, Wz, ln_g, ln_b, Wg, bg,
                                          C0g, CBg, logitsT);
  selA_kernel<<<dim3(PCH, E), 256, 0, stream>>>(logitsT, gh);
  selB_kernel<<<E, 256, 0, stream>>>(gh, boundB, countAbove);
  selC_kernel<<<dim3(PCH, E), 256, 0, stream>>>(logitsT, boundB, candCnt,
                                                candKey, candIdx);
  selD_kernel<<<E, 256, 0, stream>>>(candKey, candIdx, candCnt, countAbove,
                                     Tkey, tieCut);
  route_kernel<<<N / 256, 256, 0, stream>>>(logitsT, Tkey, tieCut, cnt,
                                            list_tok, list_w, importance);
  expert_kernel<<<dim3(N / TM, E), 512, 0, stream>>>(
      x, bw, b1, b2, W1t, W2t, A1t, B1t, A2t, B2t, cnt, list_tok, list_w, out);
  loss_kernel<<<1, 64, 0, stream>>>(importance, cnt, out + (size_t)N * O);
}

// Round 7
// 697.996 us; speedup vs baseline: 1.0878x; 1.0878x over previous
//
#include <hip/hip_runtime.h>
#include <hip/hip_bf16.h>
#include <math.h>

constexpr int N = 65536;
constexpr int C = 192;
constexpr int O = 192;
constexpr int H = 384;
constexpr int E = 8;
constexpr int B = 4;
constexpr int R = 8;
constexpr int F = 64;
constexpr int GIN = C + F + 2;   // 258
constexpr int K = 10240;
constexpr int TM = 32;           // tokens per expert-tile
constexpr int NBKT = 4096;       // 12-bit bucket histogram
constexpr int KSH = 52;          // key shift for bucket index
constexpr int PCH = 32;          // chunks per expert for select passes
constexpr int CAP = 32768;       // candidate capacity per expert (>>10x margin)
constexpr int GT = 32;           // tokens per gate block
constexpr int TCAP = 2048;       // selD tie fast-path capacity

typedef unsigned short ushort;
typedef __attribute__((ext_vector_type(8))) short bf16x8;
typedef __attribute__((ext_vector_type(4))) float f32x4;
typedef __attribute__((ext_vector_type(4))) double f64x4;
typedef __attribute__((ext_vector_type(4))) ushort ushort4v;

#define MFMA(a, b, c) __builtin_amdgcn_mfma_f32_16x16x32_bf16(a, b, c, 0, 0, 0)
#define DMFMA(a, b, c) __builtin_amdgcn_mfma_f64_16x16x4f64(a, b, c, 0, 0, 0)

__device__ inline ushort f2bf(float f) {
  union { float f; unsigned u; } v; v.f = f;
  unsigned r = v.u + 0x7FFFu + ((v.u >> 16) & 1u);
  return (ushort)(r >> 16);
}

__device__ inline unsigned long long dkey(double d) {
  unsigned long long u = (unsigned long long)__double_as_longlong(d);
  return (u & 0x8000000000000000ULL) ? ~u : (u | 0x8000000000000000ULL);
}

__device__ inline double wave_reduce_sum(double v) {
  #pragma unroll
  for (int off = 32; off; off >>= 1) v += __shfl_down(v, off);
  return v;  // valid on lane 0
}

// ---------- coalesced f32->bf16 tile transpose (per-expert matrices) ----------
__global__ __launch_bounds__(256) void transpose_bf16_kernel(
    const float* __restrict__ src, ushort* __restrict__ dst,
    int rows, int cols) {
  __shared__ float tile[32][33];
  int e = blockIdx.y;
  int tilesPerRow = cols >> 5;
  int tr = blockIdx.x / tilesPerRow;
  int tc = blockIdx.x % tilesPerRow;
  int r0 = tr * 32, c0 = tc * 32;
  const float* s = src + (size_t)e * rows * cols;
  ushort* d = dst + (size_t)e * rows * cols;
  int tx = threadIdx.x & 31, ty = threadIdx.x >> 5;   // 32 x 8
  #pragma unroll
  for (int k = 0; k < 4; ++k)
    tile[ty + 8 * k][tx] = s[(size_t)(r0 + ty + 8 * k) * cols + c0 + tx];
  __syncthreads();
  #pragma unroll
  for (int k = 0; k < 4; ++k)
    d[(size_t)(c0 + ty + 8 * k) * rows + r0 + tx] = f2bf(tile[tx][ty + 8 * k]);
}

// ---------- convert LoRA weights to bf16; precompute C0/CB ----------
__global__ __launch_bounds__(256) void convert_kernel(
    const float* __restrict__ A1, const float* __restrict__ B1,
    const float* __restrict__ A2, const float* __restrict__ B2,
    const float* __restrict__ ln_g, const float* __restrict__ ln_b,
    const float* __restrict__ Wg,
    ushort* __restrict__ A1t, ushort* __restrict__ B1t,
    ushort* __restrict__ A2t, ushort* __restrict__ B2t,
    double* __restrict__ C0g, double* __restrict__ CBg) {
  const int s3 = E * 32 * C;     // A1t[e][br][c]
  const int s4 = E * H * 32;     // B1t[e][h][br]
  const int s5 = E * 32 * H;     // A2t[e][br][h]
  const int s6 = E * O * 32;     // B2t[e][o][br]
  if (blockIdx.x == 0 && threadIdx.x < 16) {
    int e = threadIdx.x & 7;
    double acc = 0.0;
    if (threadIdx.x < 8) {
      for (int i = 0; i < GIN; ++i) acc += (double)ln_g[i] * (double)Wg[i * E + e];
      C0g[e] = acc;
    } else {
      for (int i = 0; i < GIN; ++i) acc += (double)ln_b[i] * (double)Wg[i * E + e];
      CBg[e] = acc;
    }
  }
  int tid = blockIdx.x * 256 + threadIdx.x;
  if (tid < s3) {
    int e = tid / (32 * C), rem = tid % (32 * C), br = rem / C, c = rem % C;
    int b = br >> 3, r = br & 7;
    A1t[tid] = f2bf(A1[(((size_t)e * B + b) * C + c) * R + r]);
  } else if ((tid -= s3) < s4) {
    int e = tid / (H * 32), rem = tid % (H * 32), h = rem / 32, br = rem % 32;
    B1t[tid] = f2bf(B1[((size_t)e * 32 + br) * H + h]);
  } else if ((tid -= s4) < s5) {
    int e = tid / (32 * H), rem = tid % (32 * H), br = rem / H, h = rem % H;
    int b = br >> 3, r = br & 7;
    A2t[tid] = f2bf(A2[(((size_t)e * B + b) * H + h) * R + r]);
  } else if ((tid -= s5) < s6) {
    int e = tid / (O * 32), rem = tid % (O * 32), o = rem / 32, br = rem % 32;
    B2t[tid] = f2bf(B2[((size_t)e * 32 + br) * O + o]);
  }
}

// ---------- gate: all reductions via f64 MFMA; near-zero shuffle traffic ----
__global__ __launch_bounds__(512, 4) void gate_kernel(
    const float* __restrict__ x, const float* __restrict__ xp,
    const float* __restrict__ Wz, const float* __restrict__ ln_g,
    const float* __restrict__ ln_b, const float* __restrict__ Wg,
    const float* __restrict__ bg, const double* __restrict__ C0g,
    const double* __restrict__ CBg, double* __restrict__ logitsT) {
  __shared__ float xs[GT][196];       // 25.1 KiB, row-major (MFMA A reads)
  __shared__ double Zs[GT][65];       // 16.6 KiB
  __shared__ double Wgp[256][10];     // 20 KiB: g*Wg cols 0..7, col8=1, col9=0
  __shared__ double Sp[2][16][10];    // 2.5 KiB x-GEMM k-half partials
  __shared__ double Sfin[GT][12];     // 3 KiB  S'x[t][e]
  __shared__ double Sfz[GT][12];      // 3 KiB  S'z[t][e], col8 = sum(Z)
  __shared__ double s2zs[GT];         // sum(Z^2)
  __shared__ double mus[GT], sds[GT], sxs[GT], s2xs[GT];

  int tid = threadIdx.x;
  int n0 = blockIdx.x * GT;
  int w = tid >> 6, lane = tid & 63;
  int arow = lane & 15, kg = lane >> 4;
  int tt = w >> 2, ft = w & 3;

  // ---- stage G = g.*Wg (f64) ----
  for (int u = tid; u < 256 * 8; u += 512) {
    int k = u >> 3, e = u & 7;
    Wgp[k][e] = (double)ln_g[k] * (double)Wg[k * E + e];
  }
  if (tid < 256) { Wgp[tid][8] = 1.0; Wgp[tid][9] = 0.0; }

  // ---- stage x (f32, row-major) + fused residual/LN stats ----
  {
    int t = tid >> 4, ch = tid & 15;
    const float* xr = x + (size_t)(n0 + t) * C + ch * 12;
    const float* pr = xp + (size_t)(n0 + t) * C + ch * 12;
    double pa = 0.0, pa2 = 0.0, px = 0.0, px2 = 0.0;
    #pragma unroll
    for (int j = 0; j < 3; ++j) {
      float4 xv = *(const float4*)(xr + j * 4);
      float4 pv = *(const float4*)(pr + j * 4);
      *(float4*)&xs[t][ch * 12 + j * 4] = xv;
      float xa[4] = {xv.x, xv.y, xv.z, xv.w};
      float pp[4] = {pv.x, pv.y, pv.z, pv.w};
      #pragma unroll
      for (int q2 = 0; q2 < 4; ++q2) {
        double dx = (double)xa[q2];
        px += dx; px2 += dx * dx;
        double ad = (double)fabsf(xa[q2] - pp[q2]);
        pa += ad; pa2 += ad * ad;
      }
    }
    #pragma unroll
    for (int off = 8; off; off >>= 1) {
      pa += __shfl_down(pa, off);
      pa2 += __shfl_down(pa2, off);
      px += __shfl_down(px, off);
      px2 += __shfl_down(px2, off);
    }
    if (ch == 0) {
      double mean_a = pa * (1.0 / 192.0);
      double var_a = (pa2 - pa * pa * (1.0 / 192.0)) * (1.0 / 191.0);
      var_a = var_a > 0.0 ? var_a : 0.0;
      mus[t] = log1p(mean_a);
      sds[t] = log1p(sqrt(var_a));
      sxs[t] = px; s2xs[t] = px2;
    }
  }

  // ---- decode f64 MFMA D slot->(row,col) with two probes ----
  int rowIdx[4], colIdx[4];
  {
    f64x4 z4 = {0.0, 0.0, 0.0, 0.0};
    double pr = (double)arow;
    double pk = (kg == 0) ? 1.0 : 0.0;
    f64x4 p1 = DMFMA(pr, pk, z4);
    f64x4 p2 = DMFMA(pk, pr, z4);
    #pragma unroll
    for (int d = 0; d < 4; ++d) {
      rowIdx[d] = ((int)p1[d]) & 15;
      colIdx[d] = ((int)p2[d]) & 15;
    }
  }

  __syncthreads();

  // ---- Z = x @ Wz via f64 MFMA ----
  {
    f64x4 acc[2];
    acc[0] = (f64x4){0.0, 0.0, 0.0, 0.0}; acc[1] = acc[0];
    float bxa[24];
    #pragma unroll
    for (int s = 0; s < 24; ++s)
      bxa[s] = Wz[(4 * s + kg) * F + ft * 16 + arow];
    #pragma unroll
    for (int s = 0; s < 24; ++s) {
      double a = (double)xs[tt * 16 + arow][4 * s + kg];
      acc[s & 1] = DMFMA(a, (double)bxa[s], acc[s & 1]);
    }
    #pragma unroll
    for (int s = 0; s < 24; ++s)
      bxa[s] = Wz[(96 + 4 * s + kg) * F + ft * 16 + arow];
    #pragma unroll
    for (int s = 0; s < 24; ++s) {
      double a = (double)xs[tt * 16 + arow][96 + 4 * s + kg];
      acc[s & 1] = DMFMA(a, (double)bxa[s], acc[s & 1]);
    }
    f64x4 r = acc[0] + acc[1];
    #pragma unroll
    for (int d = 0; d < 4; ++d)
      Zs[tt * 16 + rowIdx[d]][ft * 16 + colIdx[d]] = r[d];
  }
  __syncthreads();

  // ---- reduction GEMMs (f64 MFMA) ----
  int ccol = arow < 9 ? arow : 9;   // col9 holds 0.0
  f64x4 rx = {0.0, 0.0, 0.0, 0.0};  // kh==1 partial held across barrier
  int xt2 = 0;
  if (w < 4) {
    int t2 = w >> 1, kh = w & 1; xt2 = t2;
    int kbase = kh * 96;
    f64x4 acc[2];
    acc[0] = (f64x4){0.0, 0.0, 0.0, 0.0}; acc[1] = acc[0];
    #pragma unroll
    for (int s = 0; s < 24; ++s) {
      int k = kbase + 4 * s + kg;
      double a = (double)xs[t2 * 16 + arow][k];
      acc[s & 1] = DMFMA(a, Wgp[k][ccol], acc[s & 1]);
    }
    f64x4 r = acc[0] + acc[1];
    if (kh == 0) {
      #pragma unroll
      for (int d = 0; d < 4; ++d)
        if (colIdx[d] < 9) Sp[t2][rowIdx[d]][colIdx[d]] = r[d];
    } else {
      rx = r;
    }
  } else {
    int zq = w - 4; int t2 = zq & 1; int sq = zq >> 1;
    f64x4 acc[2];
    acc[0] = (f64x4){0.0, 0.0, 0.0, 0.0}; acc[1] = acc[0];
    #pragma unroll
    for (int s = 0; s < 16; ++s) {
      double a = Zs[t2 * 16 + arow][4 * s + kg];
      if (sq) a = a * a;
      acc[s & 1] = DMFMA(a, Wgp[192 + 4 * s + kg][ccol], acc[s & 1]);
    }
    f64x4 r = acc[0] + acc[1];
    if (!sq) {
      #pragma unroll
      for (int d = 0; d < 4; ++d)
        if (colIdx[d] < 9) Sfz[t2 * 16 + rowIdx[d]][colIdx[d]] = r[d];
    } else {
      #pragma unroll
      for (int d = 0; d < 4; ++d)
        if (colIdx[d] == 8) s2zs[t2 * 16 + rowIdx[d]] = r[d];
    }
  }
  __syncthreads();
  if (w < 4 && (w & 1)) {
    #pragma unroll
    for (int d = 0; d < 4; ++d)
      if (colIdx[d] < 9)
        Sfin[xt2 * 16 + rowIdx[d]][colIdx[d]] =
            rx[d] + Sp[xt2][rowIdx[d]][colIdx[d]];
  }
  __syncthreads();

  // ---- assembly: thread = t*8 + e ----
  if (tid < GT * E) {
    int t = tid >> 3, e = tid & 7;
    int n = n0 + t;
    double mu = mus[t], sd = sds[t];
    double s = sxs[t] + Sfz[t][8] + mu + sd;
    double q = s2xs[t] + s2zs[t] + mu * mu + sd * sd;
    double m_ = s * (1.0 / 258.0);
    double v_ = q * (1.0 / 258.0) - m_ * m_;
    v_ = v_ > 0.0 ? v_ : 0.0;
    double rstd = 1.0 / sqrt(v_ + 1e-5);
    double G256e = (double)ln_g[256] * (double)Wg[256 * E + e];
    double G257e = (double)ln_g[257] * (double)Wg[257 * E + e];
    double S = Sfin[t][e] + Sfz[t][e] + mu * G256e + sd * G257e;
    double logit = rstd * S - rstd * m_ * C0g[e] + CBg[e] + (double)bg[e];
    logitsT[(size_t)e * N + n] = logit;
  }
}

// ---------- select stage A: per-chunk 12-bit bucket histogram ----------
__global__ __launch_bounds__(256) void selA_kernel(
    const double* __restrict__ logitsT, unsigned* __restrict__ gh) {
  __shared__ unsigned hist[NBKT];   // 16 KiB
  int e = blockIdx.y;
  const double* L = logitsT + (size_t)e * N + blockIdx.x * (N / PCH);
  for (int i = threadIdx.x; i < NBKT; i += 256) hist[i] = 0;
  __syncthreads();
  for (int i = threadIdx.x; i < N / PCH; i += 256) {
    unsigned long long k = dkey(L[i]);
    atomicAdd(&hist[(unsigned)(k >> KSH)], 1u);
  }
  __syncthreads();
  unsigned* ghe = gh + (size_t)e * NBKT;
  for (int i = threadIdx.x; i < NBKT; i += 256) {
    unsigned v = hist[i];
    if (v) atomicAdd(&ghe[i], v);
  }
}

// ---------- select stage B: boundary bucket via parallel suffix scan ----------
__global__ __launch_bounds__(256) void selB_kernel(
    const unsigned* __restrict__ gh, int* __restrict__ boundB,
    int* __restrict__ countAbove) {
  int e = blockIdx.x;
  const unsigned* ghe = gh + (size_t)e * NBKT;
  __shared__ unsigned bsum[256];
  __shared__ int schunk;
  int tid = threadIdx.x;
  unsigned s = 0;
  int base = tid * (NBKT / 256);            // 16 buckets per thread
  #pragma unroll
  for (int i = 0; i < NBKT / 256; ++i) s += ghe[base + i];
  bsum[tid] = s;
  if (tid == 0) schunk = 0;
  __syncthreads();
  // inclusive suffix sum over chunk sums (Hillis-Steele)
  for (int off = 1; off < 256; off <<= 1) {
    unsigned add = (tid + off < 256) ? bsum[tid + off] : 0u;
    __syncthreads();
    bsum[tid] += add;
    __syncthreads();
  }
  // largest chunk t with inclusive-suffix >= K (guaranteed: total = N >= K)
  unsigned SCt = bsum[tid];
  unsigned SCn = (tid < 255) ? bsum[tid + 1] : 0u;
  if (SCt >= (unsigned)K && (tid == 255 || SCn < (unsigned)K)) schunk = tid;
  __syncthreads();
  if (tid == 0) {
    int t = schunk;
    long long rem = (t < 255) ? (long long)bsum[t + 1] : 0LL;  // above chunk t
    int b0 = t * (NBKT / 256);
    int bfound = 0;
    long long remOut = 0;
    for (int b = b0 + (NBKT / 256) - 1; b >= b0; --b) {
      unsigned hv = ghe[b];
      if (rem + (long long)hv >= (long long)K) { bfound = b; remOut = rem; break; }
      rem += hv;
    }
    boundB[e] = bfound; countAbove[e] = (int)remOut;
  }
}

// ---------- select stage C: compact boundary-bucket candidates ----------
__global__ __launch_bounds__(256) void selC_kernel(
    const double* __restrict__ logitsT, const int* __restrict__ boundB,
    int* __restrict__ candCnt, unsigned long long* __restrict__ candKey,
    int* __restrict__ candIdx) {
  int e = blockIdx.y;
  unsigned bb = (unsigned)boundB[e];
  int base = blockIdx.x * (N / PCH);
  const double* L = logitsT + (size_t)e * N;
  int lane = threadIdx.x & 63;
  unsigned long long below = (1ULL << lane) - 1ULL;
  for (int i0 = 0; i0 < N / PCH; i0 += 256) {
    int n = base + i0 + threadIdx.x;
    unsigned long long k = dkey(L[n]);
    bool match = ((unsigned)(k >> KSH) == bb);
    unsigned long long mk = __ballot(match);
    if (match) {
      int leader = __ffsll((long long)mk) - 1;
      int cbase = 0;
      if (lane == leader) cbase = atomicAdd(&candCnt[e], __popcll(mk));
      cbase = __shfl(cbase, leader);
      int pos = cbase + __popcll(mk & below);
      if (pos < CAP) {
        candKey[(size_t)e * CAP + pos] = k;
        candIdx[(size_t)e * CAP + pos] = n;
      }
    }
  }
}

// ---------- select stage D: exact radix (parallel digit scan) + tie cut ----
__global__ __launch_bounds__(256) void selD_kernel(
    const unsigned long long* __restrict__ candKey, const int* __restrict__ candIdx,
    const int* __restrict__ candCnt, const int* __restrict__ countAbove,
    unsigned long long* __restrict__ Tkey, int* __restrict__ tieCut) {
  int e = blockIdx.x;
  int c = candCnt[e]; if (c > CAP) c = CAP;
  int need = K - countAbove[e];
  const unsigned long long* keys = candKey + (size_t)e * CAP;
  const int* idxs = candIdx + (size_t)e * CAP;
  __shared__ unsigned hist[256];
  __shared__ unsigned sfx[256];
  __shared__ unsigned long long spref;
  __shared__ int srem;
  __shared__ int red[256];
  __shared__ int tieIdx[TCAP];
  __shared__ int tieCnt;
  int tid = threadIdx.x;
  if (tid == 0) { spref = 0ULL; srem = need; }
  __syncthreads();
  for (int pass = 7; pass >= 0; --pass) {
    hist[tid] = 0;
    __syncthreads();
    unsigned long long pref = spref;
    unsigned long long mhi = (pass == 7) ? 0ULL : (~0ULL << ((pass + 1) * 8));
    for (int i = tid; i < c; i += 256) {
      unsigned long long k = keys[i];
      if ((k & mhi) == pref)
        atomicAdd(&hist[(unsigned)((k >> (pass * 8)) & 0xFF)], 1u);
    }
    __syncthreads();
    // inclusive suffix sum over digit counts
    sfx[tid] = hist[tid];
    __syncthreads();
    for (int off = 1; off < 256; off <<= 1) {
      unsigned add = (tid + off < 256) ? sfx[tid + off] : 0u;
      __syncthreads();
      sfx[tid] += add;
      __syncthreads();
    }
    int rem0 = srem;
    __syncthreads();   // all threads read srem before any write
    unsigned St = sfx[tid];
    unsigned Sn = (tid < 255) ? sfx[tid + 1] : 0u;
    // boundary digit = largest b in [1,255] with S(b) >= rem0, else 0
    if (tid >= 1 && St >= (unsigned)rem0 && (tid == 255 || Sn < (unsigned)rem0)) {
      srem = rem0 - (int)Sn;
      spref = pref | ((unsigned long long)(unsigned)tid << (pass * 8));
    }
    __syncthreads();
    if (tid == 0 && sfx[1] < (unsigned)rem0) {   // no digit >=1 qualified
      srem = rem0 - (int)sfx[1];
      spref = pref;   // digit 0
    }
    __syncthreads();
  }
  unsigned long long T = spref;
  int needT = srem;  // take needT lowest-index tokens among ==T

  // ---- compact tie indices ----
  if (tid == 0) tieCnt = 0;
  __syncthreads();
  for (int i = tid; i < c; i += 256) {
    if (keys[i] == T) {
      int p = atomicAdd(&tieCnt, 1);
      if (p < TCAP) tieIdx[p] = idxs[i];
    }
  }
  __syncthreads();
  int cT = tieCnt;
  if (cT <= TCAP) {
    for (int j = tid; j < cT; j += 256) {
      int v = tieIdx[j];
      int rank = 0;
      for (int k2 = 0; k2 < cT; ++k2) rank += (tieIdx[k2] < v) ? 1 : 0;
      if (rank == needT - 1) tieCut[e] = v;
    }
    if (tid == 0) Tkey[e] = T;
    return;
  }
  // ---- fallback: global binary search (adversarial mass-tie case) ----
  int lo = 0, hi = N - 1;
  while (lo < hi) {
    int mid = (lo + hi) >> 1;
    int cnt = 0;
    for (int i = tid; i < c; i += 256)
      cnt += (keys[i] == T && idxs[i] <= mid) ? 1 : 0;
    red[tid] = cnt;
    __syncthreads();
    for (int off = 128; off; off >>= 1) {
      if (tid < off) red[tid] += red[tid + off];
      __syncthreads();
    }
    int total = red[0];
    __syncthreads();
    if (total >= needT) hi = mid; else lo = mid + 1;
  }
  if (tid == 0) { Tkey[e] = T; tieCut[e] = lo; }
}

// ---------- routing: mask, fallback, top-2 softmax, aggregated dispatch ----------
__global__ __launch_bounds__(256) void route_kernel(
    const double* __restrict__ logitsT, const unsigned long long* __restrict__ Tkey,
    const int* __restrict__ tieCut, int* __restrict__ cnt,
    int* __restrict__ list_tok, float* __restrict__ list_w,
    double* __restrict__ importance) {
  int n = blockIdx.x * 256 + threadIdx.x;
  int lane = threadIdx.x & 63;
  double l[E];
  unsigned selbits = 0;
  #pragma unroll
  for (int e = 0; e < E; ++e) {
    l[e] = logitsT[(size_t)e * N + n];
    unsigned long long k = dkey(l[e]);
    unsigned long long T = Tkey[e];
    bool sel = (k > T) || (k == T && n <= tieCut[e]);
    if (sel) selbits |= (1u << e);
  }
  if (selbits == 0) {
    int best = 0; double bv = l[0];
    #pragma unroll
    for (int e = 1; e < E; ++e) if (l[e] > bv) { bv = l[e]; best = e; }
    selbits = (1u << best);
  }
  int i0 = -1, i1 = -1;
  double v0 = -1e300, v1 = -1e300;
  #pragma unroll
  for (int e = 0; e < E; ++e) {
    if (selbits & (1u << e)) {
      double v = l[e];
      if (v > v0) { v1 = v0; i1 = i0; v0 = v; i0 = e; }
      else if (v > v1) { v1 = v; i1 = e; }
    }
  }
  double w0 = 1.0, w1 = 0.0;
  if (i1 >= 0) {
    double e1 = exp(v1 - v0);
    w0 = 1.0 / (1.0 + e1);
    w1 = e1 / (1.0 + e1);
  }
  float w0f = (float)w0;
  float w1f = (float)w1;
  bool app1 = (i1 >= 0) && (w1f > 0.0f);

  unsigned long long below = (1ULL << lane) - 1ULL;
  #pragma unroll
  for (int e = 0; e < E; ++e) {
    unsigned long long m0 = __ballot(i0 == e);
    unsigned long long m1 = __ballot(app1 && i1 == e);
    int c = __popcll(m0) + __popcll(m1);
    int basep = 0;
    if (lane == 0 && c) basep = atomicAdd(&cnt[e], c);
    basep = __shfl(basep, 0);
    if (i0 == e) {
      int idx = basep + __popcll(m0 & below);
      list_tok[e * N + idx] = n;
      list_w[e * N + idx] = w0f;
    }
    if (app1 && i1 == e) {
      int idx = basep + __popcll(m0) + __popcll(m1 & below);
      list_tok[e * N + idx] = n;
      list_w[e * N + idx] = w1f;
    }
    double v = 0.0;
    if (i0 == e) v += (double)w0f;
    if (app1 && i1 == e) v += (double)w1f;
    v = wave_reduce_sum(v);
    if (lane == 0 && v != 0.0) unsafeAtomicAdd(&importance[e], v);
  }
}

// ---------- fused expert MLP via bf16 MFMA (r3 configuration: 256 thr) ------
__global__ __launch_bounds__(256) void expert_kernel(
    const float* __restrict__ x, const float* __restrict__ bw,
    const float* __restrict__ b1g, const float* __restrict__ b2g,
    const ushort* __restrict__ W1t, const ushort* __restrict__ W2t,
    const ushort* __restrict__ A1t, const ushort* __restrict__ B1t,
    const ushort* __restrict__ A2t, const ushort* __restrict__ B2t,
    const int* __restrict__ cnt, const int* __restrict__ list_tok,
    const float* __restrict__ list_w, float* __restrict__ out) {
  int e = blockIdx.y;
  int ce = cnt[e];
  int start = blockIdx.x * TM;
  if (start >= ce) return;
  int m = ce - start; if (m > TM) m = TM;

  __shared__ ushort xs[TM][200];   // pitch 400B: 16B-aligned rows
  __shared__ ushort hs[TM][392];
  __shared__ ushort t1w[TM][40];
  __shared__ ushort t2w[TM][40];
  __shared__ int stok[TM];
  __shared__ float swt[TM];
  __shared__ float bws[TM][B];

  int tid = threadIdx.x;
  if (tid < TM) {
    int idx = start + (tid < m ? tid : 0);
    stok[tid] = list_tok[e * N + idx];
    swt[tid] = (tid < m) ? list_w[e * N + idx] : 0.0f;
  }
  __syncthreads();
  // x -> bf16 LDS: 48 float4 chunks per token (C=192)
  for (int u = tid; u < TM * 48; u += 256) {
    int t = u / 48, ch = u % 48;
    float4 v = *(const float4*)(x + (size_t)stok[t] * C + ch * 4);
    ushort4v o4;
    o4.x = f2bf(v.x); o4.y = f2bf(v.y); o4.z = f2bf(v.z); o4.w = f2bf(v.w);
    *(ushort4v*)&xs[t][ch * 4] = o4;
  }
  if (tid < TM * B) {
    int t = tid >> 2, b = tid & 3;
    bws[t][b] = bw[(size_t)stok[t] * B + b];
  }
  __syncthreads();

  int w = tid >> 6, lane = tid & 63, q = lane >> 4, mr = lane & 15;

  // ---- t1 = x @ A1e, scaled by 2*bw -> t1w (bf16, A-layout-ready)
  {
    int mt = w >> 1, nt = w & 1;
    const ushort* A1te = A1t + ((size_t)e * 32 + nt * 16 + mr) * C;
    f32x4 acc = {0.f, 0.f, 0.f, 0.f};
    #pragma unroll
    for (int ks = 0; ks < 6; ++ks) {
      bf16x8 a = *(const bf16x8*)&xs[mt * 16 + mr][ks * 32 + q * 8];
      bf16x8 b = *(const bf16x8*)(A1te + ks * 32 + q * 8);
      acc = MFMA(a, b, acc);
    }
    int brc = nt * 16 + mr, bb = brc >> 3;
    #pragma unroll
    for (int r = 0; r < 4; ++r) {
      int t = mt * 16 + q * 4 + r;
      t1w[t][brc] = f2bf(2.0f * acc[r] * bws[t][bb]);
    }
  }
  __syncthreads();

  // ---- h = gelu(x@W1 + b1 + t1w@B1)
  {
    const ushort* W1te = W1t + (size_t)e * H * C;
    const ushort* B1te = B1t + (size_t)e * H * 32;
    for (int ht = w * 6; ht < w * 6 + 6; ++ht) {
      int h = ht * 16 + mr;
      float bi = b1g[e * H + h];
      f32x4 acc0 = {bi, bi, bi, bi}, acc1 = acc0;
      bf16x8 bb = *(const bf16x8*)(B1te + h * 32 + q * 8);
      acc0 = MFMA(*(const bf16x8*)&t1w[mr][q * 8], bb, acc0);
      acc1 = MFMA(*(const bf16x8*)&t1w[16 + mr][q * 8], bb, acc1);
      #pragma unroll
      for (int ks = 0; ks < 6; ++ks) {
        bf16x8 wb = *(const bf16x8*)(W1te + (size_t)h * C + ks * 32 + q * 8);
        acc0 = MFMA(*(const bf16x8*)&xs[mr][ks * 32 + q * 8], wb, acc0);
        acc1 = MFMA(*(const bf16x8*)&xs[16 + mr][ks * 32 + q * 8], wb, acc1);
      }
      #pragma unroll
      for (int r = 0; r < 4; ++r) {
        float v0 = acc0[r], v1 = acc1[r];
        v0 = 0.5f * v0 * (1.0f + erff(v0 * 0.70710678118654752f));
        v1 = 0.5f * v1 * (1.0f + erff(v1 * 0.70710678118654752f));
        hs[q * 4 + r][h] = f2bf(v0);
        hs[16 + q * 4 + r][h] = f2bf(v1);
      }
    }
  }
  __syncthreads();

  // ---- t2 = h @ A2e, scaled by 2*bw -> t2w
  {
    int mt = w >> 1, nt = w & 1;
    const ushort* A2te = A2t + ((size_t)e * 32 + nt * 16 + mr) * H;
    f32x4 acc = {0.f, 0.f, 0.f, 0.f};
    #pragma unroll
    for (int ks = 0; ks < 12; ++ks) {
      bf16x8 a = *(const bf16x8*)&hs[mt * 16 + mr][ks * 32 + q * 8];
      bf16x8 b = *(const bf16x8*)(A2te + ks * 32 + q * 8);
      acc = MFMA(a, b, acc);
    }
    int brc = nt * 16 + mr, bb = brc >> 3;
    #pragma unroll
    for (int r = 0; r < 4; ++r) {
      int t = mt * 16 + q * 4 + r;
      t2w[t][brc] = f2bf(2.0f * acc[r] * bws[t][bb]);
    }
  }
  __syncthreads();

  // ---- y = h@W2 + b2 + t2w@B2, gate-weighted atomic scatter
  {
    const ushort* W2te = W2t + (size_t)e * O * H;
    const ushort* B2te = B2t + (size_t)e * O * 32;
    for (int ot = w * 3; ot < w * 3 + 3; ++ot) {
      int o = ot * 16 + mr;
      float bi = b2g[e * O + o];
      f32x4 acc0 = {bi, bi, bi, bi}, acc1 = acc0;
      bf16x8 bb = *(const bf16x8*)(B2te + o * 32 + q * 8);
      acc0 = MFMA(*(const bf16x8*)&t2w[mr][q * 8], bb, acc0);
      acc1 = MFMA(*(const bf16x8*)&t2w[16 + mr][q * 8], bb, acc1);
      #pragma unroll
      for (int ks = 0; ks < 12; ++ks) {
        bf16x8 wb = *(const bf16x8*)(W2te + (size_t)o * H + ks * 32 + q * 8);
        acc0 = MFMA(*(const bf16x8*)&hs[mr][ks * 32 + q * 8], wb, acc0);
        acc1 = MFMA(*(const bf16x8*)&hs[16 + mr][ks * 32 + q * 8], wb, acc1);
      }
      #pragma unroll
      for (int r = 0; r < 4; ++r) {
        int t0 = q * 4 + r, t1i = 16 + q * 4 + r;
        if (t0 < m)
          unsafeAtomicAdd(&out[(size_t)stok[t0] * O + o], swt[t0] * acc0[r]);
        if (t1i < m)
          unsafeAtomicAdd(&out[(size_t)stok[t1i] * O + o], swt[t1i] * acc1[r]);
      }
    }
  }
}

// ---------- load-balance aux loss ----------
__global__ void loss_kernel(const double* __restrict__ importance,
                            const int* __restrict__ cnt,
                            float* __restrict__ loss_out) {
  if (threadIdx.x == 0 && blockIdx.x == 0) {
    double im = 0.0, lm = 0.0;
    for (int e = 0; e < E; ++e) { im += importance[e]; lm += (double)cnt[e]; }
    im *= (1.0 / E); lm *= (1.0 / E);
    double iv = 0.0, lv = 0.0;
    for (int e = 0; e < E; ++e) {
      double di = importance[e] - im; iv += di * di;
      double dl = (double)cnt[e] - lm; lv += dl * dl;
    }
    iv *= (1.0 / E); lv *= (1.0 / E);
    double loss = (iv / (im * im + 1e-10) + lv / (lm * lm + 1e-10)) * 0.01;
    loss_out[0] = (float)loss;
  }
}

extern "C" void kernel_launch(void* const* d_in, const int* in_sizes, int n_in,
                              void* d_out, int out_size, void* d_ws, size_t ws_size,
                              hipStream_t stream) {
  const float* x    = (const float*)d_in[0];
  const float* bw   = (const float*)d_in[1];
  const float* xp   = (const float*)d_in[2];
  const float* Wz   = (const float*)d_in[3];
  const float* ln_g = (const float*)d_in[4];
  const float* ln_b = (const float*)d_in[5];
  const float* Wg   = (const float*)d_in[6];
  const float* bg   = (const float*)d_in[7];
  const float* W1   = (const float*)d_in[8];
  const float* b1   = (const float*)d_in[9];
  const float* W2   = (const float*)d_in[10];
  const float* b2   = (const float*)d_in[11];
  const float* A1   = (const float*)d_in[12];
  const float* B1   = (const float*)d_in[13];
  const float* A2   = (const float*)d_in[14];
  const float* B2   = (const float*)d_in[15];
  float* out = (float*)d_out;

  const size_t MB = 1024 * 1024;
  char* ws = (char*)d_ws;
  double* logitsT = (double*)ws;                           // 4 MiB
  int*    list_tok = (int*)(ws + 4 * MB);                  // 2 MiB
  float*  list_w   = (float*)(ws + 6 * MB);                // 2 MiB
  char*   hdr      = ws + 8 * MB;                          // 4 KiB
  unsigned long long* Tkey = (unsigned long long*)hdr;     // @0
  int*    tieCut = (int*)(hdr + 64);                       // @64
  int*    cnt    = (int*)(hdr + 96);                       // @96
  double* importance = (double*)(hdr + 128);               // @128..192
  int*    boundB = (int*)(hdr + 256);
  int*    countAbove = (int*)(hdr + 288);
  int*    candCnt = (int*)(hdr + 320);
  double* C0g = (double*)(hdr + 512);                      // @512..576
  double* CBg = (double*)(hdr + 576);                      // @576..640
  ushort* W1t = (ushort*)(ws + 8 * MB + 4096);             // ~3 MiB of bf16 weights
  ushort* W2t = W1t + (size_t)E * H * C;
  ushort* A1t = W2t + (size_t)E * O * H;
  ushort* B1t = A1t + (size_t)E * 32 * C;
  ushort* A2t = B1t + (size_t)E * H * 32;
  ushort* B2t = A2t + (size_t)E * 32 * H;
  unsigned* gh = (unsigned*)(ws + 12 * MB);                // 128 KiB
  unsigned long long* candKey = (unsigned long long*)(ws + 13 * MB);  // 2 MiB
  int* candIdx = (int*)(ws + 15 * MB);                     // 1 MiB

  hipMemsetAsync(d_out, 0, (size_t)(N * O + 1) * sizeof(float), stream);
  hipMemsetAsync(hdr + 96, 0, 352 - 96, stream);  // cnt, importance, sel headers
  hipMemsetAsync(gh, 0, (size_t)E * NBKT * sizeof(unsigned), stream);

  // big weights: coalesced LDS tile transpose; LoRA smalls: element kernel
  transpose_bf16_kernel<<<dim3((C / 32) * (H / 32), E), 256, 0, stream>>>(
      W1, W1t, C, H);
  transpose_bf16_kernel<<<dim3((H / 32) * (O / 32), E), 256, 0, stream>>>(
      W2, W2t, H, O);
  int convN = (E * 32 * C) * 2 + (E * H * 32) * 2;
  convert_kernel<<<(convN + 255) / 256, 256, 0, stream>>>(
      A1, B1, A2, B2, ln_g, ln_b, Wg, A1t, B1t, A2t, B2t, C0g, CBg);
  gate_kernel<<<N / GT, 512, 0, stream>>>(x, xp, Wz, ln_g, ln_b, Wg, bg,
                                          C0g, CBg, logitsT);
  selA_kernel<<<dim3(PCH, E), 256, 0, stream>>>(logitsT, gh);
  selB_kernel<<<E, 256, 0, stream>>>(gh, boundB, countAbove);
  selC_kernel<<<dim3(PCH, E), 256, 0, stream>>>(logitsT, boundB, candCnt,
                                                candKey, candIdx);
  selD_kernel<<<E, 256, 0, stream>>>(candKey, candIdx, candCnt, countAbove,
                                     Tkey, tieCut);
  route_kernel<<<N / 256, 256, 0, stream>>>(logitsT, Tkey, tieCut, cnt,
                                            list_tok, list_w, importance);
  expert_kernel<<<dim3(N / TM, E), 256, 0, stream>>>(
      x, bw, b1, b2, W1t, W2t, A1t, B1t, A2t, B2t, cnt, list_tok, list_w, out);
  loss_kernel<<<1, 64, 0, stream>>>(importance, cnt, out + (size_t)N * O);
}

// Round 8
// 691.003 us; speedup vs baseline: 1.0988x; 1.0101x over previous
//
#include <hip/hip_runtime.h>
#include <hip/hip_bf16.h>
#include <math.h>

constexpr int N = 65536;
constexpr int C = 192;
constexpr int O = 192;
constexpr int H = 384;
constexpr int E = 8;
constexpr int B = 4;
constexpr int R = 8;
constexpr int F = 64;
constexpr int GIN = C + F + 2;   // 258
constexpr int K = 10240;
constexpr int TM = 32;           // tokens per expert-tile
constexpr int NBKT = 4096;       // 12-bit bucket histogram
constexpr int KSH = 52;          // key shift for bucket index
constexpr int PCH = 32;          // chunks per expert for select passes
constexpr int CAP = 32768;       // candidate capacity per expert (>>10x margin)
constexpr int GT = 32;           // tokens per gate block
constexpr int TCAP = 2048;       // selD tie fast-path capacity

typedef unsigned short ushort;
typedef __attribute__((ext_vector_type(8))) short bf16x8;
typedef __attribute__((ext_vector_type(4))) float f32x4;
typedef __attribute__((ext_vector_type(4))) double f64x4;
typedef __attribute__((ext_vector_type(4))) ushort ushort4v;

#define MFMA(a, b, c) __builtin_amdgcn_mfma_f32_16x16x32_bf16(a, b, c, 0, 0, 0)
#define DMFMA(a, b, c) __builtin_amdgcn_mfma_f64_16x16x4f64(a, b, c, 0, 0, 0)

__device__ inline ushort f2bf(float f) {
  union { float f; unsigned u; } v; v.f = f;
  unsigned r = v.u + 0x7FFFu + ((v.u >> 16) & 1u);
  return (ushort)(r >> 16);
}

__device__ inline unsigned long long dkey(double d) {
  unsigned long long u = (unsigned long long)__double_as_longlong(d);
  return (u & 0x8000000000000000ULL) ? ~u : (u | 0x8000000000000000ULL);
}

__device__ inline double wave_reduce_sum(double v) {
  #pragma unroll
  for (int off = 32; off; off >>= 1) v += __shfl_down(v, off);
  return v;  // valid on lane 0
}

// ---------- prep: transposes + LoRA convert + C0/CB + workspace zeroing ----
// Fuses 6 former dispatches (2 transposes, convert, 2 memsets of gh/hdr, plus
// C0/CB) into one kernel. Block ranges: [0,576) W1-transpose, [576,1152)
// W2-transpose, [1152,2304) LoRA convert, [2304,2313) zero gh/hdr.
constexpr int NT1 = E * (C / 32) * (H / 32);     // 576
constexpr int NT2 = E * (H / 32) * (O / 32);     // 576
constexpr int NCV = 1152;                        // 294912 / 256
constexpr int NZB = 8;                           // gh zero blocks

__global__ __launch_bounds__(256) void prep_kernel(
    const float* __restrict__ W1, const float* __restrict__ W2,
    const float* __restrict__ A1, const float* __restrict__ B1,
    const float* __restrict__ A2, const float* __restrict__ B2,
    const float* __restrict__ ln_g, const float* __restrict__ ln_b,
    const float* __restrict__ Wg,
    ushort* __restrict__ W1t, ushort* __restrict__ W2t,
    ushort* __restrict__ A1t, ushort* __restrict__ B1t,
    ushort* __restrict__ A2t, ushort* __restrict__ B2t,
    double* __restrict__ C0g, double* __restrict__ CBg,
    unsigned* __restrict__ gh, unsigned* __restrict__ hdrZ) {
  __shared__ float tile[32][33];
  int b = blockIdx.x;
  int tx = threadIdx.x & 31, ty = threadIdx.x >> 5;   // 32 x 8
  if (b < NT1) {
    // ---- W1[e][C][H] f32 -> W1t[e][H][C] bf16, 32x32 tiles ----
    const int tilesPerRow = H / 32;  // 12
    int e = b / ((C / 32) * (H / 32));
    int t = b % ((C / 32) * (H / 32));
    int tr = t / tilesPerRow, tc = t % tilesPerRow;
    int r0 = tr * 32, c0 = tc * 32;
    const float* s = W1 + (size_t)e * C * H;
    ushort* d = W1t + (size_t)e * C * H;
    #pragma unroll
    for (int k = 0; k < 4; ++k)
      tile[ty + 8 * k][tx] = s[(size_t)(r0 + ty + 8 * k) * H + c0 + tx];
    __syncthreads();
    #pragma unroll
    for (int k = 0; k < 4; ++k)
      d[(size_t)(c0 + ty + 8 * k) * C + r0 + tx] = f2bf(tile[tx][ty + 8 * k]);
  } else if ((b -= NT1) < NT2) {
    // ---- W2[e][H][O] f32 -> W2t[e][O][H] bf16 ----
    const int tilesPerRow = O / 32;  // 6
    int e = b / ((H / 32) * (O / 32));
    int t = b % ((H / 32) * (O / 32));
    int tr = t / tilesPerRow, tc = t % tilesPerRow;
    int r0 = tr * 32, c0 = tc * 32;
    const float* s = W2 + (size_t)e * H * O;
    ushort* d = W2t + (size_t)e * H * O;
    #pragma unroll
    for (int k = 0; k < 4; ++k)
      tile[ty + 8 * k][tx] = s[(size_t)(r0 + ty + 8 * k) * O + c0 + tx];
    __syncthreads();
    #pragma unroll
    for (int k = 0; k < 4; ++k)
      d[(size_t)(c0 + ty + 8 * k) * H + r0 + tx] = f2bf(tile[tx][ty + 8 * k]);
  } else if ((b -= NT2) < NCV) {
    // ---- LoRA converts + C0/CB (block 0) ----
    const int s3 = E * 32 * C;     // A1t[e][br][c]
    const int s4 = E * H * 32;     // B1t[e][h][br]
    const int s5 = E * 32 * H;     // A2t[e][br][h]
    const int s6 = E * O * 32;     // B2t[e][o][br]
    if (b == 0 && threadIdx.x < 16) {
      int e = threadIdx.x & 7;
      double acc = 0.0;
      if (threadIdx.x < 8) {
        for (int i = 0; i < GIN; ++i) acc += (double)ln_g[i] * (double)Wg[i * E + e];
        C0g[e] = acc;
      } else {
        for (int i = 0; i < GIN; ++i) acc += (double)ln_b[i] * (double)Wg[i * E + e];
        CBg[e] = acc;
      }
    }
    int tid = b * 256 + threadIdx.x;
    if (tid < s3) {
      int e = tid / (32 * C), rem = tid % (32 * C), br = rem / C, c = rem % C;
      int bb = br >> 3, r = br & 7;
      A1t[tid] = f2bf(A1[(((size_t)e * B + bb) * C + c) * R + r]);
    } else if ((tid -= s3) < s4) {
      int e = tid / (H * 32), rem = tid % (H * 32), h = rem / 32, br = rem % 32;
      B1t[tid] = f2bf(B1[((size_t)e * 32 + br) * H + h]);
    } else if ((tid -= s4) < s5) {
      int e = tid / (32 * H), rem = tid % (32 * H), br = rem / H, h = rem % H;
      int bb = br >> 3, r = br & 7;
      A2t[tid] = f2bf(A2[(((size_t)e * B + bb) * H + h) * R + r]);
    } else if ((tid -= s5) < s6) {
      int e = tid / (O * 32), rem = tid % (O * 32), o = rem / 32, br = rem % 32;
      B2t[tid] = f2bf(B2[((size_t)e * 32 + br) * O + o]);
    }
  } else {
    b -= NCV;
    if (b < NZB) {
      // zero gh: E*NBKT = 32768 words over 8 blocks
      int base = b * (E * NBKT / NZB);
      for (int i = threadIdx.x; i < E * NBKT / NZB; i += 256)
        gh[base + i] = 0u;
    } else {
      // zero hdr words [24, 88): cnt, importance, boundB, countAbove, candCnt
      if (threadIdx.x < 64) hdrZ[24 + threadIdx.x] = 0u;
    }
  }
}

// ---------- gate: all reductions via f64 MFMA; near-zero shuffle traffic ----
__global__ __launch_bounds__(512, 4) void gate_kernel(
    const float* __restrict__ x, const float* __restrict__ xp,
    const float* __restrict__ Wz, const float* __restrict__ ln_g,
    const float* __restrict__ ln_b, const float* __restrict__ Wg,
    const float* __restrict__ bg, const double* __restrict__ C0g,
    const double* __restrict__ CBg, double* __restrict__ logitsT) {
  __shared__ float xs[GT][196];       // 25.1 KiB, row-major (MFMA A reads)
  __shared__ double Zs[GT][65];       // 16.6 KiB
  __shared__ double Wgp[256][10];     // 20 KiB: g*Wg cols 0..7, col8=1, col9=0
  __shared__ double Sp[2][16][10];    // 2.5 KiB x-GEMM k-half partials
  __shared__ double Sfin[GT][12];     // 3 KiB  S'x[t][e]
  __shared__ double Sfz[GT][12];      // 3 KiB  S'z[t][e], col8 = sum(Z)
  __shared__ double s2zs[GT];         // sum(Z^2)
  __shared__ double mus[GT], sds[GT], sxs[GT], s2xs[GT];

  int tid = threadIdx.x;
  int n0 = blockIdx.x * GT;
  int w = tid >> 6, lane = tid & 63;
  int arow = lane & 15, kg = lane >> 4;
  int tt = w >> 2, ft = w & 3;

  // ---- stage G = g.*Wg (f64) ----
  for (int u = tid; u < 256 * 8; u += 512) {
    int k = u >> 3, e = u & 7;
    Wgp[k][e] = (double)ln_g[k] * (double)Wg[k * E + e];
  }
  if (tid < 256) { Wgp[tid][8] = 1.0; Wgp[tid][9] = 0.0; }

  // ---- stage x (f32, row-major) + fused residual/LN stats ----
  {
    int t = tid >> 4, ch = tid & 15;
    const float* xr = x + (size_t)(n0 + t) * C + ch * 12;
    const float* pr = xp + (size_t)(n0 + t) * C + ch * 12;
    double pa = 0.0, pa2 = 0.0, px = 0.0, px2 = 0.0;
    #pragma unroll
    for (int j = 0; j < 3; ++j) {
      float4 xv = *(const float4*)(xr + j * 4);
      float4 pv = *(const float4*)(pr + j * 4);
      *(float4*)&xs[t][ch * 12 + j * 4] = xv;
      float xa[4] = {xv.x, xv.y, xv.z, xv.w};
      float pp[4] = {pv.x, pv.y, pv.z, pv.w};
      #pragma unroll
      for (int q2 = 0; q2 < 4; ++q2) {
        double dx = (double)xa[q2];
        px += dx; px2 += dx * dx;
        double ad = (double)fabsf(xa[q2] - pp[q2]);
        pa += ad; pa2 += ad * ad;
      }
    }
    #pragma unroll
    for (int off = 8; off; off >>= 1) {
      pa += __shfl_down(pa, off);
      pa2 += __shfl_down(pa2, off);
      px += __shfl_down(px, off);
      px2 += __shfl_down(px2, off);
    }
    if (ch == 0) {
      double mean_a = pa * (1.0 / 192.0);
      double var_a = (pa2 - pa * pa * (1.0 / 192.0)) * (1.0 / 191.0);
      var_a = var_a > 0.0 ? var_a : 0.0;
      mus[t] = log1p(mean_a);
      sds[t] = log1p(sqrt(var_a));
      sxs[t] = px; s2xs[t] = px2;
    }
  }

  // ---- decode f64 MFMA D slot->(row,col) with two probes ----
  int rowIdx[4], colIdx[4];
  {
    f64x4 z4 = {0.0, 0.0, 0.0, 0.0};
    double pr = (double)arow;
    double pk = (kg == 0) ? 1.0 : 0.0;
    f64x4 p1 = DMFMA(pr, pk, z4);
    f64x4 p2 = DMFMA(pk, pr, z4);
    #pragma unroll
    for (int d = 0; d < 4; ++d) {
      rowIdx[d] = ((int)p1[d]) & 15;
      colIdx[d] = ((int)p2[d]) & 15;
    }
  }

  __syncthreads();

  // ---- Z = x @ Wz via f64 MFMA ----
  {
    f64x4 acc[2];
    acc[0] = (f64x4){0.0, 0.0, 0.0, 0.0}; acc[1] = acc[0];
    float bxa[24];
    #pragma unroll
    for (int s = 0; s < 24; ++s)
      bxa[s] = Wz[(4 * s + kg) * F + ft * 16 + arow];
    #pragma unroll
    for (int s = 0; s < 24; ++s) {
      double a = (double)xs[tt * 16 + arow][4 * s + kg];
      acc[s & 1] = DMFMA(a, (double)bxa[s], acc[s & 1]);
    }
    #pragma unroll
    for (int s = 0; s < 24; ++s)
      bxa[s] = Wz[(96 + 4 * s + kg) * F + ft * 16 + arow];
    #pragma unroll
    for (int s = 0; s < 24; ++s) {
      double a = (double)xs[tt * 16 + arow][96 + 4 * s + kg];
      acc[s & 1] = DMFMA(a, (double)bxa[s], acc[s & 1]);
    }
    f64x4 r = acc[0] + acc[1];
    #pragma unroll
    for (int d = 0; d < 4; ++d)
      Zs[tt * 16 + rowIdx[d]][ft * 16 + colIdx[d]] = r[d];
  }
  __syncthreads();

  // ---- reduction GEMMs (f64 MFMA) ----
  int ccol = arow < 9 ? arow : 9;   // col9 holds 0.0
  f64x4 rx = {0.0, 0.0, 0.0, 0.0};  // kh==1 partial held across barrier
  int xt2 = 0;
  if (w < 4) {
    int t2 = w >> 1, kh = w & 1; xt2 = t2;
    int kbase = kh * 96;
    f64x4 acc[2];
    acc[0] = (f64x4){0.0, 0.0, 0.0, 0.0}; acc[1] = acc[0];
    #pragma unroll
    for (int s = 0; s < 24; ++s) {
      int k = kbase + 4 * s + kg;
      double a = (double)xs[t2 * 16 + arow][k];
      acc[s & 1] = DMFMA(a, Wgp[k][ccol], acc[s & 1]);
    }
    f64x4 r = acc[0] + acc[1];
    if (kh == 0) {
      #pragma unroll
      for (int d = 0; d < 4; ++d)
        if (colIdx[d] < 9) Sp[t2][rowIdx[d]][colIdx[d]] = r[d];
    } else {
      rx = r;
    }
  } else {
    int zq = w - 4; int t2 = zq & 1; int sq = zq >> 1;
    f64x4 acc[2];
    acc[0] = (f64x4){0.0, 0.0, 0.0, 0.0}; acc[1] = acc[0];
    #pragma unroll
    for (int s = 0; s < 16; ++s) {
      double a = Zs[t2 * 16 + arow][4 * s + kg];
      if (sq) a = a * a;
      acc[s & 1] = DMFMA(a, Wgp[192 + 4 * s + kg][ccol], acc[s & 1]);
    }
    f64x4 r = acc[0] + acc[1];
    if (!sq) {
      #pragma unroll
      for (int d = 0; d < 4; ++d)
        if (colIdx[d] < 9) Sfz[t2 * 16 + rowIdx[d]][colIdx[d]] = r[d];
    } else {
      #pragma unroll
      for (int d = 0; d < 4; ++d)
        if (colIdx[d] == 8) s2zs[t2 * 16 + rowIdx[d]] = r[d];
    }
  }
  __syncthreads();
  if (w < 4 && (w & 1)) {
    #pragma unroll
    for (int d = 0; d < 4; ++d)
      if (colIdx[d] < 9)
        Sfin[xt2 * 16 + rowIdx[d]][colIdx[d]] =
            rx[d] + Sp[xt2][rowIdx[d]][colIdx[d]];
  }
  __syncthreads();

  // ---- assembly: thread = t*8 + e ----
  if (tid < GT * E) {
    int t = tid >> 3, e = tid & 7;
    int n = n0 + t;
    double mu = mus[t], sd = sds[t];
    double s = sxs[t] + Sfz[t][8] + mu + sd;
    double q = s2xs[t] + s2zs[t] + mu * mu + sd * sd;
    double m_ = s * (1.0 / 258.0);
    double v_ = q * (1.0 / 258.0) - m_ * m_;
    v_ = v_ > 0.0 ? v_ : 0.0;
    double rstd = 1.0 / sqrt(v_ + 1e-5);
    double G256e = (double)ln_g[256] * (double)Wg[256 * E + e];
    double G257e = (double)ln_g[257] * (double)Wg[257 * E + e];
    double S = Sfin[t][e] + Sfz[t][e] + mu * G256e + sd * G257e;
    double logit = rstd * S - rstd * m_ * C0g[e] + CBg[e] + (double)bg[e];
    logitsT[(size_t)e * N + n] = logit;
  }
}

// ---------- select stage A: per-chunk 12-bit bucket histogram ----------
__global__ __launch_bounds__(256) void selA_kernel(
    const double* __restrict__ logitsT, unsigned* __restrict__ gh) {
  __shared__ unsigned hist[NBKT];   // 16 KiB
  int e = blockIdx.y;
  const double* L = logitsT + (size_t)e * N + blockIdx.x * (N / PCH);
  for (int i = threadIdx.x; i < NBKT; i += 256) hist[i] = 0;
  __syncthreads();
  for (int i = threadIdx.x; i < N / PCH; i += 256) {
    unsigned long long k = dkey(L[i]);
    atomicAdd(&hist[(unsigned)(k >> KSH)], 1u);
  }
  __syncthreads();
  unsigned* ghe = gh + (size_t)e * NBKT;
  for (int i = threadIdx.x; i < NBKT; i += 256) {
    unsigned v = hist[i];
    if (v) atomicAdd(&ghe[i], v);
  }
}

// ---------- select stage B: boundary bucket via parallel suffix scan ----------
__global__ __launch_bounds__(256) void selB_kernel(
    const unsigned* __restrict__ gh, int* __restrict__ boundB,
    int* __restrict__ countAbove) {
  int e = blockIdx.x;
  const unsigned* ghe = gh + (size_t)e * NBKT;
  __shared__ unsigned bsum[256];
  __shared__ int schunk;
  int tid = threadIdx.x;
  unsigned s = 0;
  int base = tid * (NBKT / 256);            // 16 buckets per thread
  #pragma unroll
  for (int i = 0; i < NBKT / 256; ++i) s += ghe[base + i];
  bsum[tid] = s;
  if (tid == 0) schunk = 0;
  __syncthreads();
  // inclusive suffix sum over chunk sums (Hillis-Steele)
  for (int off = 1; off < 256; off <<= 1) {
    unsigned add = (tid + off < 256) ? bsum[tid + off] : 0u;
    __syncthreads();
    bsum[tid] += add;
    __syncthreads();
  }
  unsigned SCt = bsum[tid];
  unsigned SCn = (tid < 255) ? bsum[tid + 1] : 0u;
  if (SCt >= (unsigned)K && (tid == 255 || SCn < (unsigned)K)) schunk = tid;
  __syncthreads();
  if (tid == 0) {
    int t = schunk;
    long long rem = (t < 255) ? (long long)bsum[t + 1] : 0LL;  // above chunk t
    int b0 = t * (NBKT / 256);
    int bfound = 0;
    long long remOut = 0;
    for (int b = b0 + (NBKT / 256) - 1; b >= b0; --b) {
      unsigned hv = ghe[b];
      if (rem + (long long)hv >= (long long)K) { bfound = b; remOut = rem; break; }
      rem += hv;
    }
    boundB[e] = bfound; countAbove[e] = (int)remOut;
  }
}

// ---------- select stage C: compact boundary-bucket candidates ----------
__global__ __launch_bounds__(256) void selC_kernel(
    const double* __restrict__ logitsT, const int* __restrict__ boundB,
    int* __restrict__ candCnt, unsigned long long* __restrict__ candKey,
    int* __restrict__ candIdx) {
  int e = blockIdx.y;
  unsigned bb = (unsigned)boundB[e];
  int base = blockIdx.x * (N / PCH);
  const double* L = logitsT + (size_t)e * N;
  int lane = threadIdx.x & 63;
  unsigned long long below = (1ULL << lane) - 1ULL;
  for (int i0 = 0; i0 < N / PCH; i0 += 256) {
    int n = base + i0 + threadIdx.x;
    unsigned long long k = dkey(L[n]);
    bool match = ((unsigned)(k >> KSH) == bb);
    unsigned long long mk = __ballot(match);
    if (match) {
      int leader = __ffsll((long long)mk) - 1;
      int cbase = 0;
      if (lane == leader) cbase = atomicAdd(&candCnt[e], __popcll(mk));
      cbase = __shfl(cbase, leader);
      int pos = cbase + __popcll(mk & below);
      if (pos < CAP) {
        candKey[(size_t)e * CAP + pos] = k;
        candIdx[(size_t)e * CAP + pos] = n;
      }
    }
  }
}

// ---------- select stage D: exact radix (parallel digit scan) + tie cut ----
__global__ __launch_bounds__(256) void selD_kernel(
    const unsigned long long* __restrict__ candKey, const int* __restrict__ candIdx,
    const int* __restrict__ candCnt, const int* __restrict__ countAbove,
    unsigned long long* __restrict__ Tkey, int* __restrict__ tieCut) {
  int e = blockIdx.x;
  int c = candCnt[e]; if (c > CAP) c = CAP;
  int need = K - countAbove[e];
  const unsigned long long* keys = candKey + (size_t)e * CAP;
  const int* idxs = candIdx + (size_t)e * CAP;
  __shared__ unsigned hist[256];
  __shared__ unsigned sfx[256];
  __shared__ unsigned long long spref;
  __shared__ int srem;
  __shared__ int red[256];
  __shared__ int tieIdx[TCAP];
  __shared__ int tieCnt;
  int tid = threadIdx.x;
  if (tid == 0) { spref = 0ULL; srem = need; }
  __syncthreads();
  for (int pass = 7; pass >= 0; --pass) {
    hist[tid] = 0;
    __syncthreads();
    unsigned long long pref = spref;
    unsigned long long mhi = (pass == 7) ? 0ULL : (~0ULL << ((pass + 1) * 8));
    for (int i = tid; i < c; i += 256) {
      unsigned long long k = keys[i];
      if ((k & mhi) == pref)
        atomicAdd(&hist[(unsigned)((k >> (pass * 8)) & 0xFF)], 1u);
    }
    __syncthreads();
    sfx[tid] = hist[tid];
    __syncthreads();
    for (int off = 1; off < 256; off <<= 1) {
      unsigned add = (tid + off < 256) ? sfx[tid + off] : 0u;
      __syncthreads();
      sfx[tid] += add;
      __syncthreads();
    }
    int rem0 = srem;
    __syncthreads();   // all threads read srem before any write
    unsigned St = sfx[tid];
    unsigned Sn = (tid < 255) ? sfx[tid + 1] : 0u;
    if (tid >= 1 && St >= (unsigned)rem0 && (tid == 255 || Sn < (unsigned)rem0)) {
      srem = rem0 - (int)Sn;
      spref = pref | ((unsigned long long)(unsigned)tid << (pass * 8));
    }
    __syncthreads();
    if (tid == 0 && sfx[1] < (unsigned)rem0) {   // no digit >=1 qualified
      srem = rem0 - (int)sfx[1];
      spref = pref;   // digit 0
    }
    __syncthreads();
  }
  unsigned long long T = spref;
  int needT = srem;  // take needT lowest-index tokens among ==T

  // ---- compact tie indices ----
  if (tid == 0) tieCnt = 0;
  __syncthreads();
  for (int i = tid; i < c; i += 256) {
    if (keys[i] == T) {
      int p = atomicAdd(&tieCnt, 1);
      if (p < TCAP) tieIdx[p] = idxs[i];
    }
  }
  __syncthreads();
  int cT = tieCnt;
  if (cT <= TCAP) {
    for (int j = tid; j < cT; j += 256) {
      int v = tieIdx[j];
      int rank = 0;
      for (int k2 = 0; k2 < cT; ++k2) rank += (tieIdx[k2] < v) ? 1 : 0;
      if (rank == needT - 1) tieCut[e] = v;
    }
    if (tid == 0) Tkey[e] = T;
    return;
  }
  // ---- fallback: global binary search (adversarial mass-tie case) ----
  int lo = 0, hi = N - 1;
  while (lo < hi) {
    int mid = (lo + hi) >> 1;
    int cnt = 0;
    for (int i = tid; i < c; i += 256)
      cnt += (keys[i] == T && idxs[i] <= mid) ? 1 : 0;
    red[tid] = cnt;
    __syncthreads();
    for (int off = 128; off; off >>= 1) {
      if (tid < off) red[tid] += red[tid + off];
      __syncthreads();
    }
    int total = red[0];
    __syncthreads();
    if (total >= needT) hi = mid; else lo = mid + 1;
  }
  if (tid == 0) { Tkey[e] = T; tieCut[e] = lo; }
}

// ---------- routing: zero out + mask, fallback, top-2 softmax, dispatch ----
__global__ __launch_bounds__(256) void route_kernel(
    const double* __restrict__ logitsT, const unsigned long long* __restrict__ Tkey,
    const int* __restrict__ tieCut, int* __restrict__ cnt,
    int* __restrict__ list_tok, float* __restrict__ list_w,
    double* __restrict__ importance, float* __restrict__ out) {
  int n = blockIdx.x * 256 + threadIdx.x;
  int lane = threadIdx.x & 63;
  // zero this token's output row (replaces the 50MB memset dispatch)
  {
    float4 z4 = {0.f, 0.f, 0.f, 0.f};
    float4* orow = (float4*)(out + (size_t)n * O);
    #pragma unroll
    for (int i = 0; i < O / 4; ++i) orow[i] = z4;
  }
  double l[E];
  unsigned selbits = 0;
  #pragma unroll
  for (int e = 0; e < E; ++e) {
    l[e] = logitsT[(size_t)e * N + n];
    unsigned long long k = dkey(l[e]);
    unsigned long long T = Tkey[e];
    bool sel = (k > T) || (k == T && n <= tieCut[e]);
    if (sel) selbits |= (1u << e);
  }
  if (selbits == 0) {
    int best = 0; double bv = l[0];
    #pragma unroll
    for (int e = 1; e < E; ++e) if (l[e] > bv) { bv = l[e]; best = e; }
    selbits = (1u << best);
  }
  int i0 = -1, i1 = -1;
  double v0 = -1e300, v1 = -1e300;
  #pragma unroll
  for (int e = 0; e < E; ++e) {
    if (selbits & (1u << e)) {
      double v = l[e];
      if (v > v0) { v1 = v0; i1 = i0; v0 = v; i0 = e; }
      else if (v > v1) { v1 = v; i1 = e; }
    }
  }
  double w0 = 1.0, w1 = 0.0;
  if (i1 >= 0) {
    double e1 = exp(v1 - v0);
    w0 = 1.0 / (1.0 + e1);
    w1 = e1 / (1.0 + e1);
  }
  float w0f = (float)w0;
  float w1f = (float)w1;
  bool app1 = (i1 >= 0) && (w1f > 0.0f);

  unsigned long long below = (1ULL << lane) - 1ULL;
  #pragma unroll
  for (int e = 0; e < E; ++e) {
    unsigned long long m0 = __ballot(i0 == e);
    unsigned long long m1 = __ballot(app1 && i1 == e);
    int c = __popcll(m0) + __popcll(m1);
    int basep = 0;
    if (lane == 0 && c) basep = atomicAdd(&cnt[e], c);
    basep = __shfl(basep, 0);
    if (i0 == e) {
      int idx = basep + __popcll(m0 & below);
      list_tok[e * N + idx] = n;
      list_w[e * N + idx] = w0f;
    }
    if (app1 && i1 == e) {
      int idx = basep + __popcll(m0) + __popcll(m1 & below);
      list_tok[e * N + idx] = n;
      list_w[e * N + idx] = w1f;
    }
    double v = 0.0;
    if (i0 == e) v += (double)w0f;
    if (app1 && i1 == e) v += (double)w1f;
    v = wave_reduce_sum(v);
    if (lane == 0 && v != 0.0) unsafeAtomicAdd(&importance[e], v);
  }
}

// ---------- fused expert MLP via bf16 MFMA (+ loss in block (0,0)) ----------
__global__ __launch_bounds__(256) void expert_kernel(
    const float* __restrict__ x, const float* __restrict__ bw,
    const float* __restrict__ b1g, const float* __restrict__ b2g,
    const ushort* __restrict__ W1t, const ushort* __restrict__ W2t,
    const ushort* __restrict__ A1t, const ushort* __restrict__ B1t,
    const ushort* __restrict__ A2t, const ushort* __restrict__ B2t,
    const int* __restrict__ cnt, const int* __restrict__ list_tok,
    const float* __restrict__ list_w, const double* __restrict__ importance,
    float* __restrict__ out) {
  int e = blockIdx.y;
  int tid = threadIdx.x;
  // load-balance aux loss (importance/cnt final after route; block (0,0)
  // always launches, so this replaces the separate loss dispatch)
  if (blockIdx.x == 0 && e == 0 && tid == 0) {
    double im = 0.0, lm = 0.0;
    for (int q2 = 0; q2 < E; ++q2) { im += importance[q2]; lm += (double)cnt[q2]; }
    im *= (1.0 / E); lm *= (1.0 / E);
    double iv = 0.0, lv = 0.0;
    for (int q2 = 0; q2 < E; ++q2) {
      double di = importance[q2] - im; iv += di * di;
      double dl = (double)cnt[q2] - lm; lv += dl * dl;
    }
    iv *= (1.0 / E); lv *= (1.0 / E);
    double loss = (iv / (im * im + 1e-10) + lv / (lm * lm + 1e-10)) * 0.01;
    out[(size_t)N * O] = (float)loss;
  }
  int ce = cnt[e];
  int start = blockIdx.x * TM;
  if (start >= ce) return;
  int m = ce - start; if (m > TM) m = TM;

  __shared__ ushort xs[TM][200];   // pitch 400B: 16B-aligned rows
  __shared__ ushort hs[TM][392];
  __shared__ ushort t1w[TM][40];
  __shared__ ushort t2w[TM][40];
  __shared__ int stok[TM];
  __shared__ float swt[TM];
  __shared__ float bws[TM][B];

  if (tid < TM) {
    int idx = start + (tid < m ? tid : 0);
    stok[tid] = list_tok[e * N + idx];
    swt[tid] = (tid < m) ? list_w[e * N + idx] : 0.0f;
  }
  __syncthreads();
  // x -> bf16 LDS: 48 float4 chunks per token (C=192)
  for (int u = tid; u < TM * 48; u += 256) {
    int t = u / 48, ch = u % 48;
    float4 v = *(const float4*)(x + (size_t)stok[t] * C + ch * 4);
    ushort4v o4;
    o4.x = f2bf(v.x); o4.y = f2bf(v.y); o4.z = f2bf(v.z); o4.w = f2bf(v.w);
    *(ushort4v*)&xs[t][ch * 4] = o4;
  }
  if (tid < TM * B) {
    int t = tid >> 2, b = tid & 3;
    bws[t][b] = bw[(size_t)stok[t] * B + b];
  }
  __syncthreads();

  int w = tid >> 6, lane = tid & 63, q = lane >> 4, mr = lane & 15;

  // ---- t1 = x @ A1e, scaled by 2*bw -> t1w (bf16, A-layout-ready)
  {
    int mt = w >> 1, nt = w & 1;
    const ushort* A1te = A1t + ((size_t)e * 32 + nt * 16 + mr) * C;
    f32x4 acc = {0.f, 0.f, 0.f, 0.f};
    #pragma unroll
    for (int ks = 0; ks < 6; ++ks) {
      bf16x8 a = *(const bf16x8*)&xs[mt * 16 + mr][ks * 32 + q * 8];
      bf16x8 b = *(const bf16x8*)(A1te + ks * 32 + q * 8);
      acc = MFMA(a, b, acc);
    }
    int brc = nt * 16 + mr, bb = brc >> 3;
    #pragma unroll
    for (int r = 0; r < 4; ++r) {
      int t = mt * 16 + q * 4 + r;
      t1w[t][brc] = f2bf(2.0f * acc[r] * bws[t][bb]);
    }
  }
  __syncthreads();

  // ---- h = gelu(x@W1 + b1 + t1w@B1)
  {
    const ushort* W1te = W1t + (size_t)e * H * C;
    const ushort* B1te = B1t + (size_t)e * H * 32;
    for (int ht = w * 6; ht < w * 6 + 6; ++ht) {
      int h = ht * 16 + mr;
      float bi = b1g[e * H + h];
      f32x4 acc0 = {bi, bi, bi, bi}, acc1 = acc0;
      bf16x8 bb = *(const bf16x8*)(B1te + h * 32 + q * 8);
      acc0 = MFMA(*(const bf16x8*)&t1w[mr][q * 8], bb, acc0);
      acc1 = MFMA(*(const bf16x8*)&t1w[16 + mr][q * 8], bb, acc1);
      #pragma unroll
      for (int ks = 0; ks < 6; ++ks) {
        bf16x8 wb = *(const bf16x8*)(W1te + (size_t)h * C + ks * 32 + q * 8);
        acc0 = MFMA(*(const bf16x8*)&xs[mr][ks * 32 + q * 8], wb, acc0);
        acc1 = MFMA(*(const bf16x8*)&xs[16 + mr][ks * 32 + q * 8], wb, acc1);
      }
      #pragma unroll
      for (int r = 0; r < 4; ++r) {
        float v0 = acc0[r], v1 = acc1[r];
        v0 = 0.5f * v0 * (1.0f + erff(v0 * 0.70710678118654752f));
        v1 = 0.5f * v1 * (1.0f + erff(v1 * 0.70710678118654752f));
        hs[q * 4 + r][h] = f2bf(v0);
        hs[16 + q * 4 + r][h] = f2bf(v1);
      }
    }
  }
  __syncthreads();

  // ---- t2 = h @ A2e, scaled by 2*bw -> t2w
  {
    int mt = w >> 1, nt = w & 1;
    const ushort* A2te = A2t + ((size_t)e * 32 + nt * 16 + mr) * H;
    f32x4 acc = {0.f, 0.f, 0.f, 0.f};
    #pragma unroll
    for (int ks = 0; ks < 12; ++ks) {
      bf16x8 a = *(const bf16x8*)&hs[mt * 16 + mr][ks * 32 + q * 8];
      bf16x8 b = *(const bf16x8*)(A2te + ks * 32 + q * 8);
      acc = MFMA(a, b, acc);
    }
    int brc = nt * 16 + mr, bb = brc >> 3;
    #pragma unroll
    for (int r = 0; r < 4; ++r) {
      int t = mt * 16 + q * 4 + r;
      t2w[t][brc] = f2bf(2.0f * acc[r] * bws[t][bb]);
    }
  }
  __syncthreads();

  // ---- y = h@W2 + b2 + t2w@B2, gate-weighted atomic scatter
  {
    const ushort* W2te = W2t + (size_t)e * O * H;
    const ushort* B2te = B2t + (size_t)e * O * 32;
    for (int ot = w * 3; ot < w * 3 + 3; ++ot) {
      int o = ot * 16 + mr;
      float bi = b2g[e * O + o];
      f32x4 acc0 = {bi, bi, bi, bi}, acc1 = acc0;
      bf16x8 bb = *(const bf16x8*)(B2te + o * 32 + q * 8);
      acc0 = MFMA(*(const bf16x8*)&t2w[mr][q * 8], bb, acc0);
      acc1 = MFMA(*(const bf16x8*)&t2w[16 + mr][q * 8], bb, acc1);
      #pragma unroll
      for (int ks = 0; ks < 12; ++ks) {
        bf16x8 wb = *(const bf16x8*)(W2te + (size_t)o * H + ks * 32 + q * 8);
        acc0 = MFMA(*(const bf16x8*)&hs[mr][ks * 32 + q * 8], wb, acc0);
        acc1 = MFMA(*(const bf16x8*)&hs[16 + mr][ks * 32 + q * 8], wb, acc1);
      }
      #pragma unroll
      for (int r = 0; r < 4; ++r) {
        int t0 = q * 4 + r, t1i = 16 + q * 4 + r;
        if (t0 < m)
          unsafeAtomicAdd(&out[(size_t)stok[t0] * O + o], swt[t0] * acc0[r]);
        if (t1i < m)
          unsafeAtomicAdd(&out[(size_t)stok[t1i] * O + o], swt[t1i] * acc1[r]);
      }
    }
  }
}

extern "C" void kernel_launch(void* const* d_in, const int* in_sizes, int n_in,
                              void* d_out, int out_size, void* d_ws, size_t ws_size,
                              hipStream_t stream) {
  const float* x    = (const float*)d_in[0];
  const float* bw   = (const float*)d_in[1];
  const float* xp   = (const float*)d_in[2];
  const float* Wz   = (const float*)d_in[3];
  const float* ln_g = (const float*)d_in[4];
  const float* ln_b = (const float*)d_in[5];
  const float* Wg   = (const float*)d_in[6];
  const float* bg   = (const float*)d_in[7];
  const float* W1   = (const float*)d_in[8];
  const float* b1   = (const float*)d_in[9];
  const float* W2   = (const float*)d_in[10];
  const float* b2   = (const float*)d_in[11];
  const float* A1   = (const float*)d_in[12];
  const float* B1   = (const float*)d_in[13];
  const float* A2   = (const float*)d_in[14];
  const float* B2   = (const float*)d_in[15];
  float* out = (float*)d_out;

  const size_t MB = 1024 * 1024;
  char* ws = (char*)d_ws;
  double* logitsT = (double*)ws;                           // 4 MiB
  int*    list_tok = (int*)(ws + 4 * MB);                  // 2 MiB
  float*  list_w   = (float*)(ws + 6 * MB);                // 2 MiB
  char*   hdr      = ws + 8 * MB;                          // 4 KiB
  unsigned long long* Tkey = (unsigned long long*)hdr;     // @0
  int*    tieCut = (int*)(hdr + 64);                       // @64
  int*    cnt    = (int*)(hdr + 96);                       // @96
  double* importance = (double*)(hdr + 128);               // @128..192
  int*    boundB = (int*)(hdr + 256);
  int*    countAbove = (int*)(hdr + 288);
  int*    candCnt = (int*)(hdr + 320);
  double* C0g = (double*)(hdr + 512);                      // @512..576
  double* CBg = (double*)(hdr + 576);                      // @576..640
  ushort* W1t = (ushort*)(ws + 8 * MB + 4096);             // ~3 MiB of bf16 weights
  ushort* W2t = W1t + (size_t)E * H * C;
  ushort* A1t = W2t + (size_t)E * O * H;
  ushort* B1t = A1t + (size_t)E * 32 * C;
  ushort* A2t = B1t + (size_t)E * H * 32;
  ushort* B2t = A2t + (size_t)E * 32 * H;
  unsigned* gh = (unsigned*)(ws + 12 * MB);                // 128 KiB
  unsigned long long* candKey = (unsigned long long*)(ws + 13 * MB);  // 2 MiB
  int* candIdx = (int*)(ws + 15 * MB);                     // 1 MiB

  // 8 dispatches total (was 14): prep, gate, selA, selB, selC, selD,
  // route(+out zero), expert(+loss). No memsets.
  prep_kernel<<<NT1 + NT2 + NCV + NZB + 1, 256, 0, stream>>>(
      W1, W2, A1, B1, A2, B2, ln_g, ln_b, Wg,
      W1t, W2t, A1t, B1t, A2t, B2t, C0g, CBg, gh, (unsigned*)hdr);
  gate_kernel<<<N / GT, 512, 0, stream>>>(x, xp, Wz, ln_g, ln_b, Wg, bg,
                                          C0g, CBg, logitsT);
  selA_kernel<<<dim3(PCH, E), 256, 0, stream>>>(logitsT, gh);
  selB_kernel<<<E, 256, 0, stream>>>(gh, boundB, countAbove);
  selC_kernel<<<dim3(PCH, E), 256, 0, stream>>>(logitsT, boundB, candCnt,
                                                candKey, candIdx);
  selD_kernel<<<E, 256, 0, stream>>>(candKey, candIdx, candCnt, countAbove,
                                     Tkey, tieCut);
  route_kernel<<<N / 256, 256, 0, stream>>>(logitsT, Tkey, tieCut, cnt,
                                            list_tok, list_w, importance, out);
  expert_kernel<<<dim3(N / TM, E), 256, 0, stream>>>(
      x, bw, b1, b2, W1t, W2t, A1t, B1t, A2t, B2t, cnt, list_tok, list_w,
      importance, out);
}

// Round 9
// 591.220 us; speedup vs baseline: 1.2843x; 1.1688x over previous
//
#include <hip/hip_runtime.h>
#include <hip/hip_bf16.h>
#include <math.h>

constexpr int N = 65536;
constexpr int C = 192;
constexpr int O = 192;
constexpr int H = 384;
constexpr int E = 8;
constexpr int B = 4;
constexpr int R = 8;
constexpr int F = 64;
constexpr int GIN = C + F + 2;   // 258
constexpr int K = 10240;
constexpr int TM = 32;           // tokens per expert-tile
constexpr int NBKT = 4096;       // 12-bit bucket histogram
constexpr int KSH = 52;          // key shift for bucket index
constexpr int PCH = 32;          // chunks per expert for select passes
constexpr int CAP = 32768;       // candidate capacity per expert (>>10x margin)
constexpr int GT = 32;           // tokens per gate block
constexpr int TCAP = 2048;       // selD tie fast-path capacity

typedef unsigned short ushort;
typedef __attribute__((ext_vector_type(8))) short bf16x8;
typedef __attribute__((ext_vector_type(4))) float f32x4;
typedef __attribute__((ext_vector_type(4))) double f64x4;
typedef __attribute__((ext_vector_type(4))) ushort ushort4v;

#define MFMA(a, b, c) __builtin_amdgcn_mfma_f32_16x16x32_bf16(a, b, c, 0, 0, 0)
#define DMFMA(a, b, c) __builtin_amdgcn_mfma_f64_16x16x4f64(a, b, c, 0, 0, 0)

__device__ inline ushort f2bf(float f) {
  union { float f; unsigned u; } v; v.f = f;
  unsigned r = v.u + 0x7FFFu + ((v.u >> 16) & 1u);
  return (ushort)(r >> 16);
}

__device__ inline unsigned long long dkey(double d) {
  unsigned long long u = (unsigned long long)__double_as_longlong(d);
  return (u & 0x8000000000000000ULL) ? ~u : (u | 0x8000000000000000ULL);
}

__device__ inline double wave_reduce_sum(double v) {
  #pragma unroll
  for (int off = 32; off; off >>= 1) v += __shfl_down(v, off);
  return v;  // valid on lane 0
}

// ---------- prep: transposes + LoRA convert + C0/CB + workspace zeroing ----
constexpr int NT1 = E * (C / 32) * (H / 32);     // 576
constexpr int NT2 = E * (H / 32) * (O / 32);     // 576
constexpr int NCV = 1152;                        // 294912 / 256
constexpr int NZB = 8;                           // gh zero blocks

__global__ __launch_bounds__(256) void prep_kernel(
    const float* __restrict__ W1, const float* __restrict__ W2,
    const float* __restrict__ A1, const float* __restrict__ B1,
    const float* __restrict__ A2, const float* __restrict__ B2,
    const float* __restrict__ ln_g, const float* __restrict__ ln_b,
    const float* __restrict__ Wg,
    ushort* __restrict__ W1t, ushort* __restrict__ W2t,
    ushort* __restrict__ A1t, ushort* __restrict__ B1t,
    ushort* __restrict__ A2t, ushort* __restrict__ B2t,
    double* __restrict__ C0g, double* __restrict__ CBg,
    unsigned* __restrict__ gh, unsigned* __restrict__ hdrZ) {
  __shared__ float tile[32][33];
  int b = blockIdx.x;
  int tx = threadIdx.x & 31, ty = threadIdx.x >> 5;   // 32 x 8
  if (b < NT1) {
    const int tilesPerRow = H / 32;  // 12
    int e = b / ((C / 32) * (H / 32));
    int t = b % ((C / 32) * (H / 32));
    int tr = t / tilesPerRow, tc = t % tilesPerRow;
    int r0 = tr * 32, c0 = tc * 32;
    const float* s = W1 + (size_t)e * C * H;
    ushort* d = W1t + (size_t)e * C * H;
    #pragma unroll
    for (int k = 0; k < 4; ++k)
      tile[ty + 8 * k][tx] = s[(size_t)(r0 + ty + 8 * k) * H + c0 + tx];
    __syncthreads();
    #pragma unroll
    for (int k = 0; k < 4; ++k)
      d[(size_t)(c0 + ty + 8 * k) * C + r0 + tx] = f2bf(tile[tx][ty + 8 * k]);
  } else if ((b -= NT1) < NT2) {
    const int tilesPerRow = O / 32;  // 6
    int e = b / ((H / 32) * (O / 32));
    int t = b % ((H / 32) * (O / 32));
    int tr = t / tilesPerRow, tc = t % tilesPerRow;
    int r0 = tr * 32, c0 = tc * 32;
    const float* s = W2 + (size_t)e * H * O;
    ushort* d = W2t + (size_t)e * H * O;
    #pragma unroll
    for (int k = 0; k < 4; ++k)
      tile[ty + 8 * k][tx] = s[(size_t)(r0 + ty + 8 * k) * O + c0 + tx];
    __syncthreads();
    #pragma unroll
    for (int k = 0; k < 4; ++k)
      d[(size_t)(c0 + ty + 8 * k) * H + r0 + tx] = f2bf(tile[tx][ty + 8 * k]);
  } else if ((b -= NT2) < NCV) {
    const int s3 = E * 32 * C;
    const int s4 = E * H * 32;
    const int s5 = E * 32 * H;
    const int s6 = E * O * 32;
    if (b == 0 && threadIdx.x < 16) {
      int e = threadIdx.x & 7;
      double acc = 0.0;
      if (threadIdx.x < 8) {
        for (int i = 0; i < GIN; ++i) acc += (double)ln_g[i] * (double)Wg[i * E + e];
        C0g[e] = acc;
      } else {
        for (int i = 0; i < GIN; ++i) acc += (double)ln_b[i] * (double)Wg[i * E + e];
        CBg[e] = acc;
      }
    }
    int tid = b * 256 + threadIdx.x;
    if (tid < s3) {
      int e = tid / (32 * C), rem = tid % (32 * C), br = rem / C, c = rem % C;
      int bb = br >> 3, r = br & 7;
      A1t[tid] = f2bf(A1[(((size_t)e * B + bb) * C + c) * R + r]);
    } else if ((tid -= s3) < s4) {
      int e = tid / (H * 32), rem = tid % (H * 32), h = rem / 32, br = rem % 32;
      B1t[tid] = f2bf(B1[((size_t)e * 32 + br) * H + h]);
    } else if ((tid -= s4) < s5) {
      int e = tid / (32 * H), rem = tid % (32 * H), br = rem / H, h = rem % H;
      int bb = br >> 3, r = br & 7;
      A2t[tid] = f2bf(A2[(((size_t)e * B + bb) * H + h) * R + r]);
    } else if ((tid -= s5) < s6) {
      int e = tid / (O * 32), rem = tid % (O * 32), o = rem / 32, br = rem % 32;
      B2t[tid] = f2bf(B2[((size_t)e * 32 + br) * O + o]);
    }
  } else {
    b -= NCV;
    if (b < NZB) {
      int base = b * (E * NBKT / NZB);
      for (int i = threadIdx.x; i < E * NBKT / NZB; i += 256)
        gh[base + i] = 0u;
    } else {
      // zero hdr words [64,512): candCnt, strided cntS/impS, spares
      for (int i = 64 + threadIdx.x; i < 512; i += 256) hdrZ[i] = 0u;
    }
  }
}

// ---------- gate: f64 MFMA reductions; also emits bf16 x copy for expert ----
__global__ __launch_bounds__(512, 4) void gate_kernel(
    const float* __restrict__ x, const float* __restrict__ xp,
    const float* __restrict__ Wz, const float* __restrict__ ln_g,
    const float* __restrict__ ln_b, const float* __restrict__ Wg,
    const float* __restrict__ bg, const double* __restrict__ C0g,
    const double* __restrict__ CBg, double* __restrict__ logitsT,
    ushort* __restrict__ xbf) {
  __shared__ float xs[GT][196];
  __shared__ double Zs[GT][65];
  __shared__ double Wgp[256][10];
  __shared__ double Sp[2][16][10];
  __shared__ double Sfin[GT][12];
  __shared__ double Sfz[GT][12];
  __shared__ double s2zs[GT];
  __shared__ double mus[GT], sds[GT], sxs[GT], s2xs[GT];

  int tid = threadIdx.x;
  int n0 = blockIdx.x * GT;
  int w = tid >> 6, lane = tid & 63;
  int arow = lane & 15, kg = lane >> 4;
  int tt = w >> 2, ft = w & 3;

  for (int u = tid; u < 256 * 8; u += 512) {
    int k = u >> 3, e = u & 7;
    Wgp[k][e] = (double)ln_g[k] * (double)Wg[k * E + e];
  }
  if (tid < 256) { Wgp[tid][8] = 1.0; Wgp[tid][9] = 0.0; }

  // ---- stage x (f32 LDS + bf16 global copy) + fused residual/LN stats ----
  {
    int t = tid >> 4, ch = tid & 15;
    const float* xr = x + (size_t)(n0 + t) * C + ch * 12;
    const float* pr = xp + (size_t)(n0 + t) * C + ch * 12;
    ushort* xbr = xbf + (size_t)(n0 + t) * C + ch * 12;
    double pa = 0.0, pa2 = 0.0, px = 0.0, px2 = 0.0;
    #pragma unroll
    for (int j = 0; j < 3; ++j) {
      float4 xv = *(const float4*)(xr + j * 4);
      float4 pv = *(const float4*)(pr + j * 4);
      *(float4*)&xs[t][ch * 12 + j * 4] = xv;
      ushort4v o4;
      o4.x = f2bf(xv.x); o4.y = f2bf(xv.y); o4.z = f2bf(xv.z); o4.w = f2bf(xv.w);
      *(ushort4v*)(xbr + j * 4) = o4;
      float xa[4] = {xv.x, xv.y, xv.z, xv.w};
      float pp[4] = {pv.x, pv.y, pv.z, pv.w};
      #pragma unroll
      for (int q2 = 0; q2 < 4; ++q2) {
        double dx = (double)xa[q2];
        px += dx; px2 += dx * dx;
        double ad = (double)fabsf(xa[q2] - pp[q2]);
        pa += ad; pa2 += ad * ad;
      }
    }
    #pragma unroll
    for (int off = 8; off; off >>= 1) {
      pa += __shfl_down(pa, off);
      pa2 += __shfl_down(pa2, off);
      px += __shfl_down(px, off);
      px2 += __shfl_down(px2, off);
    }
    if (ch == 0) {
      double mean_a = pa * (1.0 / 192.0);
      double var_a = (pa2 - pa * pa * (1.0 / 192.0)) * (1.0 / 191.0);
      var_a = var_a > 0.0 ? var_a : 0.0;
      mus[t] = log1p(mean_a);
      sds[t] = log1p(sqrt(var_a));
      sxs[t] = px; s2xs[t] = px2;
    }
  }

  // ---- decode f64 MFMA D slot->(row,col) with two probes ----
  int rowIdx[4], colIdx[4];
  {
    f64x4 z4 = {0.0, 0.0, 0.0, 0.0};
    double pr = (double)arow;
    double pk = (kg == 0) ? 1.0 : 0.0;
    f64x4 p1 = DMFMA(pr, pk, z4);
    f64x4 p2 = DMFMA(pk, pr, z4);
    #pragma unroll
    for (int d = 0; d < 4; ++d) {
      rowIdx[d] = ((int)p1[d]) & 15;
      colIdx[d] = ((int)p2[d]) & 15;
    }
  }

  __syncthreads();

  // ---- Z = x @ Wz via f64 MFMA ----
  {
    f64x4 acc[2];
    acc[0] = (f64x4){0.0, 0.0, 0.0, 0.0}; acc[1] = acc[0];
    float bxa[24];
    #pragma unroll
    for (int s = 0; s < 24; ++s)
      bxa[s] = Wz[(4 * s + kg) * F + ft * 16 + arow];
    #pragma unroll
    for (int s = 0; s < 24; ++s) {
      double a = (double)xs[tt * 16 + arow][4 * s + kg];
      acc[s & 1] = DMFMA(a, (double)bxa[s], acc[s & 1]);
    }
    #pragma unroll
    for (int s = 0; s < 24; ++s)
      bxa[s] = Wz[(96 + 4 * s + kg) * F + ft * 16 + arow];
    #pragma unroll
    for (int s = 0; s < 24; ++s) {
      double a = (double)xs[tt * 16 + arow][96 + 4 * s + kg];
      acc[s & 1] = DMFMA(a, (double)bxa[s], acc[s & 1]);
    }
    f64x4 r = acc[0] + acc[1];
    #pragma unroll
    for (int d = 0; d < 4; ++d)
      Zs[tt * 16 + rowIdx[d]][ft * 16 + colIdx[d]] = r[d];
  }
  __syncthreads();

  // ---- reduction GEMMs (f64 MFMA) ----
  int ccol = arow < 9 ? arow : 9;
  f64x4 rx = {0.0, 0.0, 0.0, 0.0};
  int xt2 = 0;
  if (w < 4) {
    int t2 = w >> 1, kh = w & 1; xt2 = t2;
    int kbase = kh * 96;
    f64x4 acc[2];
    acc[0] = (f64x4){0.0, 0.0, 0.0, 0.0}; acc[1] = acc[0];
    #pragma unroll
    for (int s = 0; s < 24; ++s) {
      int k = kbase + 4 * s + kg;
      double a = (double)xs[t2 * 16 + arow][k];
      acc[s & 1] = DMFMA(a, Wgp[k][ccol], acc[s & 1]);
    }
    f64x4 r = acc[0] + acc[1];
    if (kh == 0) {
      #pragma unroll
      for (int d = 0; d < 4; ++d)
        if (colIdx[d] < 9) Sp[t2][rowIdx[d]][colIdx[d]] = r[d];
    } else {
      rx = r;
    }
  } else {
    int zq = w - 4; int t2 = zq & 1; int sq = zq >> 1;
    f64x4 acc[2];
    acc[0] = (f64x4){0.0, 0.0, 0.0, 0.0}; acc[1] = acc[0];
    #pragma unroll
    for (int s = 0; s < 16; ++s) {
      double a = Zs[t2 * 16 + arow][4 * s + kg];
      if (sq) a = a * a;
      acc[s & 1] = DMFMA(a, Wgp[192 + 4 * s + kg][ccol], acc[s & 1]);
    }
    f64x4 r = acc[0] + acc[1];
    if (!sq) {
      #pragma unroll
      for (int d = 0; d < 4; ++d)
        if (colIdx[d] < 9) Sfz[t2 * 16 + rowIdx[d]][colIdx[d]] = r[d];
    } else {
      #pragma unroll
      for (int d = 0; d < 4; ++d)
        if (colIdx[d] == 8) s2zs[t2 * 16 + rowIdx[d]] = r[d];
    }
  }
  __syncthreads();
  if (w < 4 && (w & 1)) {
    #pragma unroll
    for (int d = 0; d < 4; ++d)
      if (colIdx[d] < 9)
        Sfin[xt2 * 16 + rowIdx[d]][colIdx[d]] =
            rx[d] + Sp[xt2][rowIdx[d]][colIdx[d]];
  }
  __syncthreads();

  // ---- assembly: thread = t*8 + e ----
  if (tid < GT * E) {
    int t = tid >> 3, e = tid & 7;
    int n = n0 + t;
    double mu = mus[t], sd = sds[t];
    double s = sxs[t] + Sfz[t][8] + mu + sd;
    double q = s2xs[t] + s2zs[t] + mu * mu + sd * sd;
    double m_ = s * (1.0 / 258.0);
    double v_ = q * (1.0 / 258.0) - m_ * m_;
    v_ = v_ > 0.0 ? v_ : 0.0;
    double rstd = 1.0 / sqrt(v_ + 1e-5);
    double G256e = (double)ln_g[256] * (double)Wg[256 * E + e];
    double G257e = (double)ln_g[257] * (double)Wg[257 * E + e];
    double S = Sfin[t][e] + Sfz[t][e] + mu * G256e + sd * G257e;
    double logit = rstd * S - rstd * m_ * C0g[e] + CBg[e] + (double)bg[e];
    logitsT[(size_t)e * N + n] = logit;
  }
}

// ---------- select stage A: per-chunk 12-bit bucket histogram ----------
__global__ __launch_bounds__(256) void selA_kernel(
    const double* __restrict__ logitsT, unsigned* __restrict__ gh) {
  __shared__ unsigned hist[NBKT];   // 16 KiB
  int e = blockIdx.y;
  const double* L = logitsT + (size_t)e * N + blockIdx.x * (N / PCH);
  for (int i = threadIdx.x; i < NBKT; i += 256) hist[i] = 0;
  __syncthreads();
  for (int i = threadIdx.x; i < N / PCH; i += 256) {
    unsigned long long k = dkey(L[i]);
    atomicAdd(&hist[(unsigned)(k >> KSH)], 1u);
  }
  __syncthreads();
  unsigned* ghe = gh + (size_t)e * NBKT;
  for (int i = threadIdx.x; i < NBKT; i += 256) {
    unsigned v = hist[i];
    if (v) atomicAdd(&ghe[i], v);
  }
}

// ---------- select stage B: boundary bucket via parallel suffix scan ----------
__global__ __launch_bounds__(256) void selB_kernel(
    const unsigned* __restrict__ gh, int* __restrict__ boundB,
    int* __restrict__ countAbove) {
  int e = blockIdx.x;
  const unsigned* ghe = gh + (size_t)e * NBKT;
  __shared__ unsigned bsum[256];
  __shared__ int schunk;
  int tid = threadIdx.x;
  unsigned s = 0;
  int base = tid * (NBKT / 256);            // 16 buckets per thread
  #pragma unroll
  for (int i = 0; i < NBKT / 256; ++i) s += ghe[base + i];
  bsum[tid] = s;
  if (tid == 0) schunk = 0;
  __syncthreads();
  for (int off = 1; off < 256; off <<= 1) {
    unsigned add = (tid + off < 256) ? bsum[tid + off] : 0u;
    __syncthreads();
    bsum[tid] += add;
    __syncthreads();
  }
  unsigned SCt = bsum[tid];
  unsigned SCn = (tid < 255) ? bsum[tid + 1] : 0u;
  if (SCt >= (unsigned)K && (tid == 255 || SCn < (unsigned)K)) schunk = tid;
  __syncthreads();
  if (tid == 0) {
    int t = schunk;
    long long rem = (t < 255) ? (long long)bsum[t + 1] : 0LL;
    int b0 = t * (NBKT / 256);
    int bfound = 0;
    long long remOut = 0;
    for (int b = b0 + (NBKT / 256) - 1; b >= b0; --b) {
      unsigned hv = ghe[b];
      if (rem + (long long)hv >= (long long)K) { bfound = b; remOut = rem; break; }
      rem += hv;
    }
    boundB[e] = bfound; countAbove[e] = (int)remOut;
  }
}

// ---------- select stage C: compact boundary-bucket candidates ----------
__global__ __launch_bounds__(256) void selC_kernel(
    const double* __restrict__ logitsT, const int* __restrict__ boundB,
    int* __restrict__ candCnt, unsigned long long* __restrict__ candKey,
    int* __restrict__ candIdx) {
  int e = blockIdx.y;
  unsigned bb = (unsigned)boundB[e];
  int base = blockIdx.x * (N / PCH);
  const double* L = logitsT + (size_t)e * N;
  int lane = threadIdx.x & 63;
  unsigned long long below = (1ULL << lane) - 1ULL;
  for (int i0 = 0; i0 < N / PCH; i0 += 256) {
    int n = base + i0 + threadIdx.x;
    unsigned long long k = dkey(L[n]);
    bool match = ((unsigned)(k >> KSH) == bb);
    unsigned long long mk = __ballot(match);
    if (match) {
      int leader = __ffsll((long long)mk) - 1;
      int cbase = 0;
      if (lane == leader) cbase = atomicAdd(&candCnt[e], __popcll(mk));
      cbase = __shfl(cbase, leader);
      int pos = cbase + __popcll(mk & below);
      if (pos < CAP) {
        candKey[(size_t)e * CAP + pos] = k;
        candIdx[(size_t)e * CAP + pos] = n;
      }
    }
  }
}

// ---------- select stage D: exact radix (parallel digit scan) + tie cut ----
__global__ __launch_bounds__(256) void selD_kernel(
    const unsigned long long* __restrict__ candKey, const int* __restrict__ candIdx,
    const int* __restrict__ candCnt, const int* __restrict__ countAbove,
    unsigned long long* __restrict__ Tkey, int* __restrict__ tieCut) {
  int e = blockIdx.x;
  int c = candCnt[e]; if (c > CAP) c = CAP;
  int need = K - countAbove[e];
  const unsigned long long* keys = candKey + (size_t)e * CAP;
  const int* idxs = candIdx + (size_t)e * CAP;
  __shared__ unsigned hist[256];
  __shared__ unsigned sfx[256];
  __shared__ unsigned long long spref;
  __shared__ int srem;
  __shared__ int red[256];
  __shared__ int tieIdx[TCAP];
  __shared__ int tieCnt;
  int tid = threadIdx.x;
  if (tid == 0) { spref = 0ULL; srem = need; }
  __syncthreads();
  for (int pass = 7; pass >= 0; --pass) {
    hist[tid] = 0;
    __syncthreads();
    unsigned long long pref = spref;
    unsigned long long mhi = (pass == 7) ? 0ULL : (~0ULL << ((pass + 1) * 8));
    for (int i = tid; i < c; i += 256) {
      unsigned long long k = keys[i];
      if ((k & mhi) == pref)
        atomicAdd(&hist[(unsigned)((k >> (pass * 8)) & 0xFF)], 1u);
    }
    __syncthreads();
    sfx[tid] = hist[tid];
    __syncthreads();
    for (int off = 1; off < 256; off <<= 1) {
      unsigned add = (tid + off < 256) ? sfx[tid + off] : 0u;
      __syncthreads();
      sfx[tid] += add;
      __syncthreads();
    }
    int rem0 = srem;
    __syncthreads();
    unsigned St = sfx[tid];
    unsigned Sn = (tid < 255) ? sfx[tid + 1] : 0u;
    if (tid >= 1 && St >= (unsigned)rem0 && (tid == 255 || Sn < (unsigned)rem0)) {
      srem = rem0 - (int)Sn;
      spref = pref | ((unsigned long long)(unsigned)tid << (pass * 8));
    }
    __syncthreads();
    if (tid == 0 && sfx[1] < (unsigned)rem0) {
      srem = rem0 - (int)sfx[1];
      spref = pref;
    }
    __syncthreads();
  }
  unsigned long long T = spref;
  int needT = srem;

  if (tid == 0) tieCnt = 0;
  __syncthreads();
  for (int i = tid; i < c; i += 256) {
    if (keys[i] == T) {
      int p = atomicAdd(&tieCnt, 1);
      if (p < TCAP) tieIdx[p] = idxs[i];
    }
  }
  __syncthreads();
  int cT = tieCnt;
  if (cT <= TCAP) {
    for (int j = tid; j < cT; j += 256) {
      int v = tieIdx[j];
      int rank = 0;
      for (int k2 = 0; k2 < cT; ++k2) rank += (tieIdx[k2] < v) ? 1 : 0;
      if (rank == needT - 1) tieCut[e] = v;
    }
    if (tid == 0) Tkey[e] = T;
    return;
  }
  int lo = 0, hi = N - 1;
  while (lo < hi) {
    int mid = (lo + hi) >> 1;
    int cnt = 0;
    for (int i = tid; i < c; i += 256)
      cnt += (keys[i] == T && idxs[i] <= mid) ? 1 : 0;
    red[tid] = cnt;
    __syncthreads();
    for (int off = 128; off; off >>= 1) {
      if (tid < off) red[tid] += red[tid + off];
      __syncthreads();
    }
    int total = red[0];
    __syncthreads();
    if (total >= needT) hi = mid; else lo = mid + 1;
  }
  if (tid == 0) { Tkey[e] = T; tieCut[e] = lo; }
}

// ---------- routing: zero out, top-2 softmax, BLOCK-AGGREGATED dispatch ----
// cntS/impS are 64B-strided per expert (cntS[e*16], impS[e*8]) so the 8
// experts' atomics hit distinct lines; one atomic per expert per block.
__global__ __launch_bounds__(256) void route_kernel(
    const double* __restrict__ logitsT, const unsigned long long* __restrict__ Tkey,
    const int* __restrict__ tieCut, int* __restrict__ cntS,
    int* __restrict__ list_tok, float* __restrict__ list_w,
    double* __restrict__ impS, float* __restrict__ out) {
  __shared__ int wcnt[4][E];
  __shared__ int wbase[4][E];
  __shared__ double wimp[4][E];
  __shared__ unsigned long long wm0[4][E], wm1[4][E];
  int tid = threadIdx.x;
  int n = blockIdx.x * 256 + tid;
  int wv = tid >> 6, lane = tid & 63;
  // zero this token's output row (replaces the 50MB memset dispatch)
  {
    float4 z4 = {0.f, 0.f, 0.f, 0.f};
    float4* orow = (float4*)(out + (size_t)n * O);
    #pragma unroll
    for (int i = 0; i < O / 4; ++i) orow[i] = z4;
  }
  double l[E];
  unsigned selbits = 0;
  #pragma unroll
  for (int e = 0; e < E; ++e) {
    l[e] = logitsT[(size_t)e * N + n];
    unsigned long long k = dkey(l[e]);
    unsigned long long T = Tkey[e];
    bool sel = (k > T) || (k == T && n <= tieCut[e]);
    if (sel) selbits |= (1u << e);
  }
  if (selbits == 0) {
    int best = 0; double bv = l[0];
    #pragma unroll
    for (int e = 1; e < E; ++e) if (l[e] > bv) { bv = l[e]; best = e; }
    selbits = (1u << best);
  }
  int i0 = -1, i1 = -1;
  double v0 = -1e300, v1 = -1e300;
  #pragma unroll
  for (int e = 0; e < E; ++e) {
    if (selbits & (1u << e)) {
      double v = l[e];
      if (v > v0) { v1 = v0; i1 = i0; v0 = v; i0 = e; }
      else if (v > v1) { v1 = v; i1 = e; }
    }
  }
  double w0 = 1.0, w1 = 0.0;
  if (i1 >= 0) {
    double e1 = exp(v1 - v0);
    w0 = 1.0 / (1.0 + e1);
    w1 = e1 / (1.0 + e1);
  }
  float w0f = (float)w0;
  float w1f = (float)w1;
  bool app1 = (i1 >= 0) && (w1f > 0.0f);

  unsigned long long below = (1ULL << lane) - 1ULL;
  // pass 1: per-wave masks, counts, importance partials
  #pragma unroll
  for (int e = 0; e < E; ++e) {
    unsigned long long m0 = __ballot(i0 == e);
    unsigned long long m1 = __ballot(app1 && i1 == e);
    double v = 0.0;
    if (i0 == e) v += (double)w0f;
    if (app1 && i1 == e) v += (double)w1f;
    v = wave_reduce_sum(v);
    if (lane == 0) {
      wm0[wv][e] = m0; wm1[wv][e] = m1;
      wcnt[wv][e] = __popcll(m0) + __popcll(m1);
      wimp[wv][e] = v;
    }
  }
  __syncthreads();
  // block aggregation: one atomic per expert per block
  if (tid < E) {
    int e = tid;
    int c0 = wcnt[0][e], c1 = wcnt[1][e], c2 = wcnt[2][e], c3 = wcnt[3][e];
    int tot = c0 + c1 + c2 + c3;
    int base = tot ? atomicAdd(&cntS[e * 16], tot) : 0;
    wbase[0][e] = base;
    wbase[1][e] = base + c0;
    wbase[2][e] = base + c0 + c1;
    wbase[3][e] = base + c0 + c1 + c2;
    double s = wimp[0][e] + wimp[1][e] + wimp[2][e] + wimp[3][e];
    if (s != 0.0) unsafeAtomicAdd(&impS[e * 8], s);
  }
  __syncthreads();
  // pass 2: place entries
  #pragma unroll
  for (int e = 0; e < E; ++e) {
    unsigned long long m0 = wm0[wv][e], m1 = wm1[wv][e];
    int basep = wbase[wv][e];
    if (i0 == e) {
      int idx = basep + __popcll(m0 & below);
      list_tok[e * N + idx] = n;
      list_w[e * N + idx] = w0f;
    }
    if (app1 && i1 == e) {
      int idx = basep + __popcll(m0) + __popcll(m1 & below);
      list_tok[e * N + idx] = n;
      list_w[e * N + idx] = w1f;
    }
  }
}

// ---------- fused expert MLP via bf16 MFMA (+ loss in block (0,0)) ----------
__global__ __launch_bounds__(256) void expert_kernel(
    const ushort* __restrict__ xbf, const float* __restrict__ bw,
    const float* __restrict__ b1g, const float* __restrict__ b2g,
    const ushort* __restrict__ W1t, const ushort* __restrict__ W2t,
    const ushort* __restrict__ A1t, const ushort* __restrict__ B1t,
    const ushort* __restrict__ A2t, const ushort* __restrict__ B2t,
    const int* __restrict__ cntS, const int* __restrict__ list_tok,
    const float* __restrict__ list_w, const double* __restrict__ impS,
    float* __restrict__ out) {
  int e = blockIdx.y;
  int tid = threadIdx.x;
  if (blockIdx.x == 0 && e == 0 && tid == 0) {
    double im = 0.0, lm = 0.0;
    for (int q2 = 0; q2 < E; ++q2) { im += impS[q2 * 8]; lm += (double)cntS[q2 * 16]; }
    im *= (1.0 / E); lm *= (1.0 / E);
    double iv = 0.0, lv = 0.0;
    for (int q2 = 0; q2 < E; ++q2) {
      double di = impS[q2 * 8] - im; iv += di * di;
      double dl = (double)cntS[q2 * 16] - lm; lv += dl * dl;
    }
    iv *= (1.0 / E); lv *= (1.0 / E);
    double loss = (iv / (im * im + 1e-10) + lv / (lm * lm + 1e-10)) * 0.01;
    out[(size_t)N * O] = (float)loss;
  }
  int ce = cntS[e * 16];
  int start = blockIdx.x * TM;
  if (start >= ce) return;
  int m = ce - start; if (m > TM) m = TM;

  __shared__ ushort xs[TM][200];   // pitch 400B: 16B-aligned rows
  __shared__ ushort hs[TM][392];
  __shared__ ushort t1w[TM][40];
  __shared__ ushort t2w[TM][40];
  __shared__ int stok[TM];
  __shared__ float swt[TM];
  __shared__ float bws[TM][B];

  if (tid < TM) {
    int idx = start + (tid < m ? tid : 0);
    stok[tid] = list_tok[e * N + idx];
    swt[tid] = (tid < m) ? list_w[e * N + idx] : 0.0f;
  }
  __syncthreads();
  // bf16 x gather: 24 x 16B chunks per token (C=192, half the bytes of f32)
  for (int u = tid; u < TM * 24; u += 256) {
    int t = u / 24, ch = u % 24;
    *(bf16x8*)&xs[t][ch * 8] = *(const bf16x8*)(xbf + (size_t)stok[t] * C + ch * 8);
  }
  if (tid < TM * B) {
    int t = tid >> 2, b = tid & 3;
    bws[t][b] = bw[(size_t)stok[t] * B + b];
  }
  __syncthreads();

  int w = tid >> 6, lane = tid & 63, q = lane >> 4, mr = lane & 15;

  // ---- t1 = x @ A1e, scaled by 2*bw -> t1w (bf16, A-layout-ready)
  {
    int mt = w >> 1, nt = w & 1;
    const ushort* A1te = A1t + ((size_t)e * 32 + nt * 16 + mr) * C;
    f32x4 acc = {0.f, 0.f, 0.f, 0.f};
    #pragma unroll
    for (int ks = 0; ks < 6; ++ks) {
      bf16x8 a = *(const bf16x8*)&xs[mt * 16 + mr][ks * 32 + q * 8];
      bf16x8 b = *(const bf16x8*)(A1te + ks * 32 + q * 8);
      acc = MFMA(a, b, acc);
    }
    int brc = nt * 16 + mr, bb = brc >> 3;
    #pragma unroll
    for (int r = 0; r < 4; ++r) {
      int t = mt * 16 + q * 4 + r;
      t1w[t][brc] = f2bf(2.0f * acc[r] * bws[t][bb]);
    }
  }
  __syncthreads();

  // ---- h = gelu(x@W1 + b1 + t1w@B1)
  {
    const ushort* W1te = W1t + (size_t)e * H * C;
    const ushort* B1te = B1t + (size_t)e * H * 32;
    for (int ht = w * 6; ht < w * 6 + 6; ++ht) {
      int h = ht * 16 + mr;
      float bi = b1g[e * H + h];
      f32x4 acc0 = {bi, bi, bi, bi}, acc1 = acc0;
      bf16x8 bb = *(const bf16x8*)(B1te + h * 32 + q * 8);
      acc0 = MFMA(*(const bf16x8*)&t1w[mr][q * 8], bb, acc0);
      acc1 = MFMA(*(const bf16x8*)&t1w[16 + mr][q * 8], bb, acc1);
      #pragma unroll
      for (int ks = 0; ks < 6; ++ks) {
        bf16x8 wb = *(const bf16x8*)(W1te + (size_t)h * C + ks * 32 + q * 8);
        acc0 = MFMA(*(const bf16x8*)&xs[mr][ks * 32 + q * 8], wb, acc0);
        acc1 = MFMA(*(const bf16x8*)&xs[16 + mr][ks * 32 + q * 8], wb, acc1);
      }
      #pragma unroll
      for (int r = 0; r < 4; ++r) {
        float v0 = acc0[r], v1 = acc1[r];
        v0 = 0.5f * v0 * (1.0f + erff(v0 * 0.70710678118654752f));
        v1 = 0.5f * v1 * (1.0f + erff(v1 * 0.70710678118654752f));
        hs[q * 4 + r][h] = f2bf(v0);
        hs[16 + q * 4 + r][h] = f2bf(v1);
      }
    }
  }
  __syncthreads();

  // ---- t2 = h @ A2e, scaled by 2*bw -> t2w
  {
    int mt = w >> 1, nt = w & 1;
    const ushort* A2te = A2t + ((size_t)e * 32 + nt * 16 + mr) * H;
    f32x4 acc = {0.f, 0.f, 0.f, 0.f};
    #pragma unroll
    for (int ks = 0; ks < 12; ++ks) {
      bf16x8 a = *(const bf16x8*)&hs[mt * 16 + mr][ks * 32 + q * 8];
      bf16x8 b = *(const bf16x8*)(A2te + ks * 32 + q * 8);
      acc = MFMA(a, b, acc);
    }
    int brc = nt * 16 + mr, bb = brc >> 3;
    #pragma unroll
    for (int r = 0; r < 4; ++r) {
      int t = mt * 16 + q * 4 + r;
      t2w[t][brc] = f2bf(2.0f * acc[r] * bws[t][bb]);
    }
  }
  __syncthreads();

  // ---- y = h@W2 + b2 + t2w@B2, gate-weighted atomic scatter
  {
    const ushort* W2te = W2t + (size_t)e * O * H;
    const ushort* B2te = B2t + (size_t)e * O * 32;
    for (int ot = w * 3; ot < w * 3 + 3; ++ot) {
      int o = ot * 16 + mr;
      float bi = b2g[e * O + o];
      f32x4 acc0 = {bi, bi, bi, bi}, acc1 = acc0;
      bf16x8 bb = *(const bf16x8*)(B2te + o * 32 + q * 8);
      acc0 = MFMA(*(const bf16x8*)&t2w[mr][q * 8], bb, acc0);
      acc1 = MFMA(*(const bf16x8*)&t2w[16 + mr][q * 8], bb, acc1);
      #pragma unroll
      for (int ks = 0; ks < 12; ++ks) {
        bf16x8 wb = *(const bf16x8*)(W2te + (size_t)o * H + ks * 32 + q * 8);
        acc0 = MFMA(*(const bf16x8*)&hs[mr][ks * 32 + q * 8], wb, acc0);
        acc1 = MFMA(*(const bf16x8*)&hs[16 + mr][ks * 32 + q * 8], wb, acc1);
      }
      #pragma unroll
      for (int r = 0; r < 4; ++r) {
        int t0 = q * 4 + r, t1i = 16 + q * 4 + r;
        if (t0 < m)
          unsafeAtomicAdd(&out[(size_t)stok[t0] * O + o], swt[t0] * acc0[r]);
        if (t1i < m)
          unsafeAtomicAdd(&out[(size_t)stok[t1i] * O + o], swt[t1i] * acc1[r]);
      }
    }
  }
}

extern "C" void kernel_launch(void* const* d_in, const int* in_sizes, int n_in,
                              void* d_out, int out_size, void* d_ws, size_t ws_size,
                              hipStream_t stream) {
  const float* x    = (const float*)d_in[0];
  const float* bw   = (const float*)d_in[1];
  const float* xp   = (const float*)d_in[2];
  const float* Wz   = (const float*)d_in[3];
  const float* ln_g = (const float*)d_in[4];
  const float* ln_b = (const float*)d_in[5];
  const float* Wg   = (const float*)d_in[6];
  const float* bg   = (const float*)d_in[7];
  const float* W1   = (const float*)d_in[8];
  const float* b1   = (const float*)d_in[9];
  const float* W2   = (const float*)d_in[10];
  const float* b2   = (const float*)d_in[11];
  const float* A1   = (const float*)d_in[12];
  const float* B1   = (const float*)d_in[13];
  const float* A2   = (const float*)d_in[14];
  const float* B2   = (const float*)d_in[15];
  float* out = (float*)d_out;

  const size_t MB = 1024 * 1024;
  char* ws = (char*)d_ws;
  double* logitsT = (double*)ws;                           // 4 MiB
  int*    list_tok = (int*)(ws + 4 * MB);                  // 2 MiB
  float*  list_w   = (float*)(ws + 6 * MB);                // 2 MiB
  char*   hdr      = ws + 8 * MB;                          // 4 KiB
  unsigned long long* Tkey = (unsigned long long*)hdr;     // @0
  int*    tieCut = (int*)(hdr + 64);                       // @64
  int*    boundB = (int*)(hdr + 256);
  int*    countAbove = (int*)(hdr + 288);
  int*    candCnt = (int*)(hdr + 320);
  double* C0g = (double*)(hdr + 512);                      // @512..576
  double* CBg = (double*)(hdr + 576);                      // @576..640
  int*    cntS = (int*)(hdr + 1024);                       // 8 x 64B-strided
  double* impS = (double*)(hdr + 1536);                    // 8 x 64B-strided
  ushort* W1t = (ushort*)(ws + 8 * MB + 4096);             // ~3 MiB of bf16 weights
  ushort* W2t = W1t + (size_t)E * H * C;
  ushort* A1t = W2t + (size_t)E * O * H;
  ushort* B1t = A1t + (size_t)E * 32 * C;
  ushort* A2t = B1t + (size_t)E * H * 32;
  ushort* B2t = A2t + (size_t)E * 32 * H;
  unsigned* gh = (unsigned*)(ws + 12 * MB);                // 128 KiB
  unsigned long long* candKey = (unsigned long long*)(ws + 13 * MB);  // 2 MiB
  int* candIdx = (int*)(ws + 15 * MB);                     // 1 MiB
  ushort* xbf = (ushort*)(ws + 16 * MB);                   // 24 MiB bf16 x

  prep_kernel<<<NT1 + NT2 + NCV + NZB + 1, 256, 0, stream>>>(
      W1, W2, A1, B1, A2, B2, ln_g, ln_b, Wg,
      W1t, W2t, A1t, B1t, A2t, B2t, C0g, CBg, gh, (unsigned*)hdr);
  gate_kernel<<<N / GT, 512, 0, stream>>>(x, xp, Wz, ln_g, ln_b, Wg, bg,
                                          C0g, CBg, logitsT, xbf);
  selA_kernel<<<dim3(PCH, E), 256, 0, stream>>>(logitsT, gh);
  selB_kernel<<<E, 256, 0, stream>>>(gh, boundB, countAbove);
  selC_kernel<<<dim3(PCH, E), 256, 0, stream>>>(logitsT, boundB, candCnt,
                                                candKey, candIdx);
  selD_kernel<<<E, 256, 0, stream>>>(candKey, candIdx, candCnt, countAbove,
                                     Tkey, tieCut);
  route_kernel<<<N / 256, 256, 0, stream>>>(logitsT, Tkey, tieCut, cntS,
                                            list_tok, list_w, impS, out);
  expert_kernel<<<dim3(N / TM, E), 256, 0, stream>>>(
      xbf, bw, b1, b2, W1t, W2t, A1t, B1t, A2t, B2t, cntS, list_tok, list_w,
      impS, out);
}